// Round 14
// baseline (377.169 us; speedup 1.0000x reference)
//
#include <hip/hip_runtime.h>
#include <hip/hip_bf16.h>
#include <math.h>

// ---------------------------------------------------------------------------
// MultiLayerAttention on MI355X (gfx950)
// B=2 S=1024 H=2048 NH=16 HD=128 L=4, fp32 in/out, bf16 MFMA internally.
// R14: (a) attn reverted to R10 (256thr, 2 blocks/CU -- R13's 512thr/1blk
// lockstepped, +8us). (b) gemm_kv epilogues rebuilt: two-pass LDS-staged
// coalesced stores (was 32B/2B scattered -> 80MB RMW amplification);
// K-group applies RoPE in the store phase and writes final head-major K
// directly (rope-K kernel deleted). Obuf re-aliased to prev_bf region.
// ---------------------------------------------------------------------------

typedef __bf16 bf16;
typedef __bf16 bf16x4v __attribute__((ext_vector_type(4)));
typedef __bf16 bf16x8 __attribute__((ext_vector_type(8)));
typedef float f32x4 __attribute__((ext_vector_type(4)));

#define DEV static __device__ __forceinline__

DEV void gload_lds16(const void* g, void* s) {
  __builtin_amdgcn_global_load_lds(
      (const __attribute__((address_space(1))) void*)g,
      (__attribute__((address_space(3))) void*)s, 16, 0, 0);
}

DEV f32x4 mfma16(bf16x8 a, bf16x8 b, f32x4 c) {
  return __builtin_amdgcn_mfma_f32_16x16x32_bf16(a, b, c, 0, 0, 0);
}

// ---------------- fp32 -> bf16 conversion (vectorized) ----------------
__global__ __launch_bounds__(256) void cvt_kernel(const float* __restrict__ in,
                                                  bf16* __restrict__ out, int n4) {
  int i = blockIdx.x * 256 + threadIdx.x;
  if (i >= n4) return;
  const float4 v = ((const float4*)in)[i];
  bf16x4v o;
  o.x = (bf16)v.x; o.y = (bf16)v.y; o.z = (bf16)v.z; o.w = (bf16)v.w;
  ((bf16x4v*)out)[i] = o;
}

// ---------------- W [K=2048][N=2048] fp32 -> Wt [N][K] bf16 ----------------
__global__ __launch_bounds__(256) void twt_kernel(const float* __restrict__ W,
                                                  bf16* __restrict__ Wt) {
  __shared__ float tile[64][65];
  const int t = threadIdx.x;
  const int n0 = blockIdx.x * 64, k0 = blockIdx.y * 64;
#pragma unroll
  for (int ph = 0; ph < 16; ++ph) {
    int idx = ph * 256 + t, r = idx >> 6, c = idx & 63;
    tile[r][c] = W[(size_t)(k0 + r) * 2048 + n0 + c];
  }
  __syncthreads();
#pragma unroll
  for (int ph = 0; ph < 16; ++ph) {
    int idx = ph * 256 + t, r = idx >> 6, c = idx & 63;
    Wt[(size_t)(n0 + r) * 2048 + k0 + c] = (bf16)tile[c][r];
  }
}

// ---------------- RoPE tables ----------------
__global__ __launch_bounds__(64) void rope_table_kernel(float* __restrict__ cosT,
                                                        float* __restrict__ sinT) {
  int s = blockIdx.x, j = threadIdx.x;
  float inv = powf(10000.0f, -(float)j * (1.0f / 64.0f));
  float a = (float)s * inv;
  cosT[s * 64 + j] = cosf(a);
  sinT[s * 64 + j] = sinf(a);
}

// ---------------- RoPE in head-major layout, vectorized (Q only now) -------
__global__ __launch_bounds__(256) void rope_kernel(const bf16* __restrict__ raw,
                                                   const float* __restrict__ cosT,
                                                   const float* __restrict__ sinT,
                                                   bf16* __restrict__ outp) {
  int rid = blockIdx.x * 16 + (threadIdx.x >> 4);
  int j = threadIdx.x & 15;  // d0 = 4*j
  int s = rid & 1023;
  const bf16* src = raw + (size_t)rid * 128 + 4 * j;
  bf16* dst = outp + (size_t)rid * 128 + 4 * j;
  bf16x4v x1 = *(const bf16x4v*)src;
  bf16x4v x2 = *(const bf16x4v*)(src + 64);
  f32x4 c = *(const f32x4*)(cosT + s * 64 + 4 * j);
  f32x4 sn = *(const f32x4*)(sinT + s * 64 + 4 * j);
  bf16x4v o1, o2;
#pragma unroll
  for (int k = 0; k < 4; ++k) {
    float a = (float)x1[k], b2 = (float)x2[k];
    o1[k] = (bf16)(a * c[k] - b2 * sn[k]);
    o2[k] = (bf16)(b2 * c[k] + a * sn[k]);
  }
  *(bf16x4v*)dst = o1;
  *(bf16x4v*)(dst + 64) = o2;
}

// ---------------- mean over S (two-stage, deterministic) ----------------
__global__ __launch_bounds__(256) void mean_part_kernel(const float* __restrict__ hs,
                                                        float* __restrict__ part) {
  int bc = blockIdx.x;                 // 0..15: b*8 + colchunk
  int b = bc >> 3, c0 = (bc & 7) * 256;
  int ss = blockIdx.y;                 // 0..7
  int col = c0 + threadIdx.x;
  float s = 0.f;
  for (int r = 0; r < 128; ++r)
    s += hs[((size_t)b * 1024 + ss * 128 + r) * 2048 + col];
  part[(size_t)ss * 4096 + b * 2048 + col] = s;
}

__global__ __launch_bounds__(256) void mean_fin_kernel(const float* __restrict__ part,
                                                       float* __restrict__ meanb) {
  int c = blockIdx.x * 256 + threadIdx.x;  // 0..4095
  float s = 0.f;
#pragma unroll
  for (int j = 0; j < 8; ++j) s += part[(size_t)j * 4096 + c];
  meanb[c] = s * (1.0f / 1024.0f);
}

// ---------------- gate: softmax(mean @ Wg) -> layer_w[2][4] ----------------
__global__ __launch_bounds__(256) void gate_kernel(const float* __restrict__ meanb,
                                                   const float* __restrict__ Wg,
                                                   float* __restrict__ lwout) {
  __shared__ float red[8][256];
  int t = threadIdx.x;
  float p[8];
#pragma unroll
  for (int j = 0; j < 8; ++j) p[j] = 0.f;
  for (int hh = t; hh < 2048; hh += 256) {
    float m0 = meanb[hh], m1 = meanb[2048 + hh];
#pragma unroll
    for (int ll = 0; ll < 4; ++ll) {
      float g = Wg[hh * 4 + ll];
      p[ll] += m0 * g;
      p[4 + ll] += m1 * g;
    }
  }
#pragma unroll
  for (int j = 0; j < 8; ++j) red[j][t] = p[j];
  __syncthreads();
  for (int s2 = 128; s2 > 0; s2 >>= 1) {
    if (t < s2) {
#pragma unroll
      for (int j = 0; j < 8; ++j) red[j][t] += red[j][t + s2];
    }
    __syncthreads();
  }
  if (t == 0) {
#pragma unroll
    for (int bb = 0; bb < 2; ++bb) {
      float v0 = red[bb * 4 + 0][0], v1 = red[bb * 4 + 1][0];
      float v2 = red[bb * 4 + 2][0], v3 = red[bb * 4 + 3][0];
      float mx = fmaxf(fmaxf(v0, v1), fmaxf(v2, v3));
      float e0 = __expf(v0 - mx), e1 = __expf(v1 - mx);
      float e2 = __expf(v2 - mx), e3 = __expf(v3 - mx);
      float inv = 1.0f / (e0 + e1 + e2 + e3);
      lwout[bb * 4 + 0] = e0 * inv;
      lwout[bb * 4 + 1] = e1 * inv;
      lwout[bb * 4 + 2] = e2 * inv;
      lwout[bb * 4 + 3] = e3 * inv;
    }
  }
}

// ---------------- GEMM (128^2): C = A[M][K] @ Bt[N][K]^T + bias -------------
// Used for Q (OUTMODE 3) and O (OUTMODE 1) projections only.
template <int OUTMODE>
__global__ __launch_bounds__(256) void gemm_kernel(const bf16* __restrict__ A,
                                                   const bf16* __restrict__ Bt,
                                                   const float* __restrict__ bias,
                                                   void* __restrict__ Cout,
                                                   int M, int N, int K) {
  __shared__ __attribute__((aligned(16))) bf16 As[2][128 * 64];
  __shared__ __attribute__((aligned(16))) bf16 Bs[2][128 * 64];
  const int t = threadIdx.x;
  const int w = t >> 6, l = t & 63;
  const int lo = l & 15, hi = l >> 4;
  const int wr = w >> 1, wc = w & 1;

  const int nwg = gridDim.x * gridDim.y;
  int flat = blockIdx.y * gridDim.x + blockIdx.x;
  int swz = (flat & 7) * (nwg >> 3) + (flat >> 3);
  const int bx = swz % gridDim.x, by = swz / gridDim.x;

  f32x4 acc[4][4];
#pragma unroll
  for (int m = 0; m < 4; ++m)
#pragma unroll
    for (int n = 0; n < 4; ++n)
#pragma unroll
      for (int q = 0; q < 4; ++q) acc[m][n][q] = 0.f;

  int srow[4], scl[4];
#pragma unroll
  for (int p = 0; p < 4; ++p) {
    int id = p * 256 + t;
    int r = id >> 3, cph = id & 7;
    srow[p] = r;
    scl[p] = cph ^ (r & 7);
  }

  const bf16* Ab = A + (size_t)by * 128 * K;
  const bf16* Bb = Bt + (size_t)bx * 128 * K;

  auto stage = [&](int bi, int kt) {
#pragma unroll
    for (int p = 0; p < 4; ++p)
      gload_lds16(Ab + (size_t)srow[p] * K + kt + scl[p] * 8,
                  &As[bi][(p * 256 + w * 64) * 8]);
#pragma unroll
    for (int p = 0; p < 4; ++p)
      gload_lds16(Bb + (size_t)srow[p] * K + kt + scl[p] * 8,
                  &Bs[bi][(p * 256 + w * 64) * 8]);
  };

  stage(0, 0);
  int cur = 0;
  for (int kt = 0; kt < K; kt += 64) {
    if (kt + 64 < K) {
      stage(cur ^ 1, kt + 64);
      asm volatile("s_waitcnt vmcnt(8)" ::: "memory");
    } else {
      asm volatile("s_waitcnt vmcnt(0)" ::: "memory");
    }
    __builtin_amdgcn_s_barrier();
    __builtin_amdgcn_sched_barrier(0);
    __builtin_amdgcn_s_setprio(1);
#pragma unroll
    for (int ks = 0; ks < 2; ++ks) {
      bf16x8 af[4], bfr[4];
#pragma unroll
      for (int m = 0; m < 4; ++m) {
        int row = wr * 64 + m * 16 + lo;
        int ch = (ks * 4 + hi) ^ (row & 7);
        af[m] = *(const bf16x8*)&As[cur][row * 64 + ch * 8];
      }
#pragma unroll
      for (int n = 0; n < 4; ++n) {
        int row = wc * 64 + n * 16 + lo;
        int ch = (ks * 4 + hi) ^ (row & 7);
        bfr[n] = *(const bf16x8*)&Bs[cur][row * 64 + ch * 8];
      }
#pragma unroll
      for (int m = 0; m < 4; ++m)
#pragma unroll
        for (int n = 0; n < 4; ++n)
          acc[m][n] = mfma16(af[m], bfr[n], acc[m][n]);
    }
    __builtin_amdgcn_s_setprio(0);
    __builtin_amdgcn_s_barrier();
    cur ^= 1;
  }

#pragma unroll
  for (int n = 0; n < 4; ++n) {
    int col = bx * 128 + wc * 64 + n * 16 + lo;
    float bb = bias[col];
#pragma unroll
    for (int m = 0; m < 4; ++m) {
#pragma unroll
      for (int i = 0; i < 4; ++i) {
        size_t row = (size_t)by * 128 + wr * 64 + m * 16 + hi * 4 + i;
        float v = acc[m][n][i] + bb;
        if (OUTMODE == 1)
          ((float*)Cout)[row * N + col] = v;
        else if (OUTMODE == 0)
          ((bf16*)Cout)[row * N + col] = (bf16)v;
        else {  // 3: head-major
          size_t g = (row >> 10) * 16 + (col >> 7);
          ((bf16*)Cout)[(g * 1024 + (row & 1023)) * 128 + (col & 127)] = (bf16)v;
        }
      }
    }
  }
}

// ---------------- fused K+V projection GEMM, 256^2 tile, 8-phase ------------
// Main loop as R12. NEW epilogues: two-pass LDS-staged coalesced stores.
// Pass p stages rows wm==p into SH[rowl*264+coll] (row stride 528B: scalar
// write conflicts <=2-way), then 512 jobs emit 128B-contiguous stores.
// K-group applies RoPE in the store phase (final head-major K, no rope pass).
// V-group reads sigma-inverse positions (token = p5*32+p2*16+(p4p3)*4+p1p0).
__global__ __launch_bounds__(512, 2) void gemm_kv_kernel(
    const bf16* __restrict__ prev, const bf16* __restrict__ WkT,
    const bf16* __restrict__ WvT, const float* __restrict__ bk,
    const float* __restrict__ bv, const float* __restrict__ cosT,
    const float* __restrict__ sinT, bf16* __restrict__ Kout,
    bf16* __restrict__ Vout) {
  __shared__ __attribute__((aligned(16))) bf16 SH[65536];  // 128KB
  bf16* AsP0 = SH;            // [16384] x2 dbuf
  bf16* BsP0 = SH + 32768;
  const int t = threadIdx.x;
  const int w = t >> 6, l = t & 63;
  const int lo = l & 15, hi = l >> 4;
  const int wm = w >> 2, wn = w & 3;

  const int bid = blockIdx.x;
  const int grp = bid >> 8;   // 0: K = prev(M) x WkT(N); 1: V^T = WvT(M) x prev(N)
  const int sub = bid & 255;
  const int swz = (sub & 7) * 32 + (sub >> 3);
  const int mt = (grp == 0) ? (swz >> 3) : (swz & 7);
  const int nt = (grp == 0) ? (swz & 7) : (swz >> 3);
  const bf16* Ab = ((grp == 0) ? prev : WvT) + (size_t)mt * 256 * 2048;
  const bf16* Bb = ((grp == 0) ? WkT : prev) + (size_t)nt * 256 * 2048;

  const int r0 = t >> 2;
  const int c8 = ((t & 3) ^ ((r0 >> 1) & 3)) * 8;

  f32x4 acc[8][4];
#pragma unroll
  for (int m = 0; m < 8; ++m)
#pragma unroll
    for (int n = 0; n < 4; ++n)
#pragma unroll
      for (int q = 0; q < 4; ++q) acc[m][n][q] = 0.f;

  auto gA = [&](int bi, int kh, int p, int koff) {
    gload_lds16(Ab + (size_t)(p * 128 + r0) * 2048 + koff + kh * 32 + c8,
                &AsP0[bi * 16384 + kh * 8192 + p * 4096 + w * 512]);
  };
  auto gB = [&](int bi, int kh, int p, int koff) {
    gload_lds16(Bb + (size_t)(p * 128 + r0) * 2048 + koff + kh * 32 + c8,
                &BsP0[bi * 16384 + kh * 8192 + p * 4096 + w * 512]);
  };

  gA(0, 0, 0, 0); gA(0, 0, 1, 0);
  gB(0, 0, 0, 0); gB(0, 0, 1, 0);
  gA(0, 1, 0, 0); gA(0, 1, 1, 0);
  gB(0, 1, 0, 0); gB(0, 1, 1, 0);
  asm volatile("s_waitcnt vmcnt(4)" ::: "memory");
  __builtin_amdgcn_s_barrier();

  int cur = 0;
  for (int kt = 0; kt < 32; ++kt) {
    const int nxt = cur ^ 1;
    const int koff = (kt + 1) * 64;
    const bool pf = kt < 31;
    bf16x8 af[8], bfr[2];
    const bf16* Acur = AsP0 + cur * 16384;
    const bf16* Bcur = BsP0 + cur * 16384;

    // ---------- phase 0: ks=0, n {0,1} ----------
#pragma unroll
    for (int m = 0; m < 8; ++m) {
      int row = wm * 128 + m * 16 + lo;
      int slot = hi ^ ((row >> 1) & 3);
      af[m] = *(const bf16x8*)&Acur[row * 32 + slot * 8];
    }
#pragma unroll
    for (int n = 0; n < 2; ++n) {
      int row = wn * 64 + n * 16 + lo;
      int slot = hi ^ ((row >> 1) & 3);
      bfr[n] = *(const bf16x8*)&Bcur[row * 32 + slot * 8];
    }
    if (pf) { gA(nxt, 0, 0, koff); gA(nxt, 0, 1, koff); }
    __builtin_amdgcn_s_barrier();
    __builtin_amdgcn_s_setprio(1);
#pragma unroll
    for (int m = 0; m < 8; ++m) {
      acc[m][0] = mfma16(af[m], bfr[0], acc[m][0]);
      acc[m][1] = mfma16(af[m], bfr[1], acc[m][1]);
    }
    __builtin_amdgcn_s_setprio(0);
    __builtin_amdgcn_s_barrier();

    // ---------- phase 1: ks=0, n {2,3} ----------
#pragma unroll
    for (int n = 0; n < 2; ++n) {
      int row = wn * 64 + (n + 2) * 16 + lo;
      int slot = hi ^ ((row >> 1) & 3);
      bfr[n] = *(const bf16x8*)&Bcur[row * 32 + slot * 8];
    }
    if (pf) {
      gB(nxt, 0, 0, koff); gB(nxt, 0, 1, koff);
      asm volatile("s_waitcnt vmcnt(4)" ::: "memory");
    } else {
      asm volatile("s_waitcnt vmcnt(0)" ::: "memory");
    }
    __builtin_amdgcn_s_barrier();
    __builtin_amdgcn_s_setprio(1);
#pragma unroll
    for (int m = 0; m < 8; ++m) {
      acc[m][2] = mfma16(af[m], bfr[0], acc[m][2]);
      acc[m][3] = mfma16(af[m], bfr[1], acc[m][3]);
    }
    __builtin_amdgcn_s_setprio(0);
    __builtin_amdgcn_s_barrier();

    // ---------- phase 2: ks=1, n {0,1} ----------
#pragma unroll
    for (int m = 0; m < 8; ++m) {
      int row = wm * 128 + m * 16 + lo;
      int slot = hi ^ ((row >> 1) & 3);
      af[m] = *(const bf16x8*)&Acur[8192 + row * 32 + slot * 8];
    }
#pragma unroll
    for (int n = 0; n < 2; ++n) {
      int row = wn * 64 + n * 16 + lo;
      int slot = hi ^ ((row >> 1) & 3);
      bfr[n] = *(const bf16x8*)&Bcur[8192 + row * 32 + slot * 8];
    }
    if (pf) { gA(nxt, 1, 0, koff); gA(nxt, 1, 1, koff); }
    __builtin_amdgcn_s_barrier();
    __builtin_amdgcn_s_setprio(1);
#pragma unroll
    for (int m = 0; m < 8; ++m) {
      acc[m][0] = mfma16(af[m], bfr[0], acc[m][0]);
      acc[m][1] = mfma16(af[m], bfr[1], acc[m][1]);
    }
    __builtin_amdgcn_s_setprio(0);
    __builtin_amdgcn_s_barrier();

    // ---------- phase 3: ks=1, n {2,3} ----------
#pragma unroll
    for (int n = 0; n < 2; ++n) {
      int row = wn * 64 + (n + 2) * 16 + lo;
      int slot = hi ^ ((row >> 1) & 3);
      bfr[n] = *(const bf16x8*)&Bcur[8192 + row * 32 + slot * 8];
    }
    if (pf) {
      gB(nxt, 1, 0, koff); gB(nxt, 1, 1, koff);
      asm volatile("s_waitcnt vmcnt(4)" ::: "memory");
    } else {
      asm volatile("s_waitcnt vmcnt(0)" ::: "memory");
    }
    __builtin_amdgcn_s_barrier();
    __builtin_amdgcn_s_setprio(1);
#pragma unroll
    for (int m = 0; m < 8; ++m) {
      acc[m][2] = mfma16(af[m], bfr[0], acc[m][2]);
      acc[m][3] = mfma16(af[m], bfr[1], acc[m][3]);
    }
    __builtin_amdgcn_s_setprio(0);
    __builtin_amdgcn_s_barrier();

    cur = nxt;
  }

  // -------- two-pass LDS-staged coalesced epilogue (SH reused) --------
#pragma unroll
  for (int p = 0; p < 2; ++p) {
    if (wm == p) {
      // stage this half's 128x256 tile into SH[rowl*264 + coll] (+bias)
#pragma unroll
      for (int m = 0; m < 8; ++m) {
#pragma unroll
        for (int i = 0; i < 4; ++i) {
          int rowl = m * 16 + hi * 4 + i;
          float rb = (grp == 1) ? bv[(size_t)mt * 256 + p * 128 + rowl] : 0.f;
#pragma unroll
          for (int n = 0; n < 4; ++n) {
            int coll = wn * 64 + n * 16 + lo;
            float bb = (grp == 0) ? bk[nt * 256 + coll] : rb;
            SH[rowl * 264 + coll] = (bf16)(acc[m][n][i] + bb);
          }
        }
      }
    }
    __builtin_amdgcn_s_barrier();

    if (grp == 0) {
      // K store: job = (token rowl, head, half); RoPE applied; 128B stores
      int tokl = t >> 2, head = (t >> 1) & 1, half = t & 1;
      size_t grow = (size_t)mt * 256 + p * 128 + tokl;
      int s_idx = (int)(grow & 1023);
      size_t gg = (grow >> 10) * 16 + nt * 2 + head;
      const bf16* x1p = &SH[tokl * 264 + head * 128];
      const bf16* x2p = x1p + 64;
      bf16* dst = Kout + (gg * 1024 + s_idx) * 128 + half * 64;
      const float* cp = cosT + s_idx * 64;
      const float* sp = sinT + s_idx * 64;
#pragma unroll
      for (int cb = 0; cb < 8; ++cb) {
        bf16x8 x1 = *(const bf16x8*)(x1p + cb * 8);
        bf16x8 x2 = *(const bf16x8*)(x2p + cb * 8);
        bf16x8 o;
#pragma unroll
        for (int k = 0; k < 8; ++k) {
          float cc = cp[cb * 8 + k], ss = sp[cb * 8 + k];
          float a = (float)x1[k], b2 = (float)x2[k];
          o[k] = (bf16)(half ? (b2 * cc + a * ss) : (a * cc - b2 * ss));
        }
        *(bf16x8*)(dst + cb * 8) = o;
      }
    } else {
      // V store: job = (feat rowl, 64-token sigma block q); 16B stores
      int featl = t >> 2, q = t & 3;
      size_t feat_g = (size_t)mt * 256 + p * 128 + featl;
      int tokbase = nt * 256 + q * 64;
      bf16* dst = Vout + (size_t)(tokbase >> 10) * 2097152 + feat_g * 1024 +
                  (tokbase & 1023);
      const bf16* src = &SH[featl * 264 + q * 64];
#pragma unroll
      for (int o16 = 0; o16 < 8; ++o16) {
        int tb = (o16 >> 2) * 32 + (o16 & 3) * 4;
        bf16x4v lo4 = *(const bf16x4v*)(src + tb);
        bf16x4v hi4 = *(const bf16x4v*)(src + tb + 16);
        bf16x8 o = __builtin_shufflevector(lo4, hi4, 0, 1, 2, 3, 4, 5, 6, 7);
        *(bf16x8*)(dst + o16 * 8) = o;
      }
    }
    __builtin_amdgcn_s_barrier();  // WAR before pass 2 overwrites SH
  }
}

// ---------------- fused flash attention (R10 verbatim) ----------
// grid (B*NH=32, S/128=8, L=4), 256 threads (4 waves, 2 q-subtiles each).
__global__ __launch_bounds__(256, 2) void attn_kernel(const bf16* __restrict__ Q,
                                                      const bf16* __restrict__ Kb,
                                                      const bf16* __restrict__ Vt,
                                                      const float* __restrict__ lw,
                                                      bf16* __restrict__ Obuf) {
  __shared__ __attribute__((aligned(16))) bf16 Ks[2][64 * 128];
  __shared__ __attribute__((aligned(16))) bf16 Vs[2][128 * 64];
  const int t = threadIdx.x, w = t >> 6, l = t & 63;
  const int lo = l & 15, hi = l >> 4;
  const int bh = blockIdx.x;  // b*16+h
  const int qt = blockIdx.y;  // 128-row q tile
  const int li = blockIdx.z;
  const int b = bh >> 4, h = bh & 15;
  const float C2 = 0.08838834764831845f * 1.44269504f;
  const float M2 = 64.0f * C2;

  bf16x8 qf[2][4];
#pragma unroll
  for (int qs = 0; qs < 2; ++qs) {
    const bf16* qptr =
        Q + ((size_t)bh * 1024 + qt * 128 + w * 32 + qs * 16 + lo) * 128;
#pragma unroll
    for (int db = 0; db < 4; ++db)
      qf[qs][db] = *(const bf16x8*)(qptr + db * 32 + hi * 8);
  }

  int krow[4], kcl[4], vrow[4], vcl[4];
#pragma unroll
  for (int p = 0; p < 4; ++p) {
    int id = p * 256 + t;
    krow[p] = id >> 4;
    kcl[p] = (id & 15) ^ (krow[p] & 7);
    vrow[p] = id >> 3;
    vcl[p] = (id & 7) ^ (vrow[p] & 7);
  }

  const bf16* Kl = Kb + ((size_t)li * 32 + bh) * (size_t)131072;
  const bf16* Vl = Vt + ((size_t)li * 32 + bh) * (size_t)131072;

  float si0 = 0.f, si1 = 0.f;
  f32x4 oacc[2][8];
#pragma unroll
  for (int qs = 0; qs < 2; ++qs)
#pragma unroll
    for (int dc = 0; dc < 8; ++dc)
#pragma unroll
      for (int q = 0; q < 4; ++q) oacc[qs][dc][q] = 0.f;

  auto stage = [&](int bi, int kt2) {
    const bf16* Ksrc = Kl + (size_t)kt2 * 8192;
#pragma unroll
    for (int p = 0; p < 4; ++p)
      gload_lds16(Ksrc + (size_t)krow[p] * 128 + kcl[p] * 8,
                  &Ks[bi][(p * 256 + w * 64) * 8]);
#pragma unroll
    for (int p = 0; p < 4; ++p)
      gload_lds16(Vl + (size_t)vrow[p] * 1024 + kt2 * 64 + vcl[p] * 8,
                  &Vs[bi][(p * 256 + w * 64) * 8]);
  };

  auto softmax_step = [&](f32x4 (&sa)[4], float& si, bf16x8 (&pf2)[2]) {
    float rs = 0.f;
    bf16x4v pk[4];
#pragma unroll
    for (int kc = 0; kc < 4; ++kc) {
#pragma unroll
      for (int i = 0; i < 4; ++i) {
        float pf_ = __builtin_amdgcn_exp2f(fmaf(sa[kc][i], C2, -M2));
        rs += pf_;
        pk[kc][i] = (bf16)pf_;
      }
    }
    rs += __shfl_xor(rs, 16);
    rs += __shfl_xor(rs, 32);
    si += rs;
    pf2[0] = __builtin_shufflevector(pk[0], pk[1], 0, 1, 2, 3, 4, 5, 6, 7);
    pf2[1] = __builtin_shufflevector(pk[2], pk[3], 0, 1, 2, 3, 4, 5, 6, 7);
  };

  stage(0, 0);
  int cur = 0;
  for (int kt = 0; kt < 16; ++kt) {
    if (kt < 15) {
      stage(cur ^ 1, kt + 1);
      asm volatile("s_waitcnt vmcnt(8)" ::: "memory");
    } else {
      asm volatile("s_waitcnt vmcnt(0)" ::: "memory");
    }
    __builtin_amdgcn_s_barrier();
    __builtin_amdgcn_sched_barrier(0);

    f32x4 sa[2][4];
#pragma unroll
    for (int qs = 0; qs < 2; ++qs)
#pragma unroll
      for (int kc = 0; kc < 4; ++kc)
#pragma unroll
        for (int q = 0; q < 4; ++q) sa[qs][kc][q] = 0.f;
    __builtin_amdgcn_s_setprio(1);
#pragma unroll
    for (int kc = 0; kc < 4; ++kc) {
      int row = kc * 16 + lo;
#pragma unroll
      for (int db = 0; db < 4; ++db) {
        int ch = (db * 4 + hi) ^ (row & 7);
        bf16x8 kf = *(const bf16x8*)&Ks[cur][row * 128 + ch * 8];
        sa[0][kc] = mfma16(kf, qf[0][db], sa[0][kc]);
        sa[1][kc] = mfma16(kf, qf[1][db], sa[1][kc]);
      }
    }
    __builtin_amdgcn_s_setprio(0);

    bf16x8 pfr[2][2];
    softmax_step(sa[0], si0, pfr[0]);
    softmax_step(sa[1], si1, pfr[1]);

    __builtin_amdgcn_s_setprio(1);
#pragma unroll
    for (int kvc = 0; kvc < 2; ++kvc) {
#pragma unroll
      for (int dc = 0; dc < 8; ++dc) {
        int rowv = dc * 16 + lo;
        int ch = (kvc * 4 + hi) ^ (rowv & 7);
        bf16x8 vf = *(const bf16x8*)&Vs[cur][rowv * 64 + ch * 8];
        oacc[0][dc] = mfma16(pfr[0][kvc], vf, oacc[0][dc]);
        oacc[1][dc] = mfma16(pfr[1][kvc], vf, oacc[1][dc]);
      }
    }
    __builtin_amdgcn_s_setprio(0);
    __builtin_amdgcn_s_barrier();
    cur ^= 1;
  }

  float wl = lw[b * 4 + li];
#pragma unroll
  for (int qs = 0; qs < 2; ++qs) {
    float sv = (qs == 0) ? si0 : si1;
    float inv[4];
#pragma unroll
    for (int i = 0; i < 4; ++i) inv[i] = wl / __shfl(sv, hi * 4 + i);
#pragma unroll
    for (int dc = 0; dc < 8; ++dc) {
      int col = h * 128 + dc * 16 + lo;
#pragma unroll
      for (int i = 0; i < 4; ++i) {
        int srow = qt * 128 + w * 32 + qs * 16 + hi * 4 + i;
        Obuf[((size_t)(li * 2 + b) * 1024 + srow) * 2048 + col] =
            (bf16)(oacc[qs][dc][i] * inv[i]);
      }
    }
  }
}

// ---------------- layer combine: comb = sum_l Obuf[l] ----------------
__global__ __launch_bounds__(256) void comb_kernel(const bf16* __restrict__ Obuf,
                                                   bf16* __restrict__ comb) {
  size_t i = ((size_t)blockIdx.x * 256 + threadIdx.x) * 8;
  bf16x8 a0 = *(const bf16x8*)(Obuf + i);
  bf16x8 a1 = *(const bf16x8*)(Obuf + 4194304 + i);
  bf16x8 a2 = *(const bf16x8*)(Obuf + 8388608 + i);
  bf16x8 a3 = *(const bf16x8*)(Obuf + 12582912 + i);
  bf16x8 o;
#pragma unroll
  for (int j = 0; j < 8; ++j)
    o[j] = (bf16)((float)a0[j] + (float)a1[j] + (float)a2[j] + (float)a3[j]);
  *(bf16x8*)(comb + i) = o;
}

// ---------------------------------------------------------------------------
extern "C" void kernel_launch(void* const* d_in, const int* in_sizes, int n_in,
                              void* d_out, int out_size, void* d_ws, size_t ws_size,
                              hipStream_t stream) {
  (void)in_sizes; (void)n_in; (void)out_size; (void)ws_size;
  const float* hs = (const float*)d_in[0];     // [2,1024,2048]
  const float* prev = (const float*)d_in[1];   // [4,2,1024,2048]
  const float* Wq = (const float*)d_in[2];
  const float* bq = (const float*)d_in[3];
  const float* Wk = (const float*)d_in[4];
  const float* bk = (const float*)d_in[5];
  const float* Wv = (const float*)d_in[6];
  const float* bv = (const float*)d_in[7];
  const float* Wo = (const float*)d_in[8];
  const float* bo = (const float*)d_in[9];
  const float* Wg = (const float*)d_in[10];
  float* out = (float*)d_out;

  char* ws = (char*)d_ws;
  bf16* hs_bf = (bf16*)(ws + 0);                  //  8MB ; later Qbf, then comb
  bf16* prev_bf = (bf16*)(ws + 8388608);          // 32MB ; later Obuf
  bf16* WqT = (bf16*)(ws + 41943040);             //  8MB
  bf16* WkT = (bf16*)(ws + 50331648);             //  8MB
  bf16* WvT = (bf16*)(ws + 58720256);             //  8MB
  bf16* Qraw2 = (bf16*)(ws + 67108864);           //  8MB (head-major Q)
  bf16* WoT = (bf16*)(ws + 75497472);             //  8MB
  bf16* Kbf = (bf16*)(ws + 83886080);             // 32MB final rope'd K (from gemm_kv)
  bf16* Vt = (bf16*)(ws + 117440512);             // 32MB (V^T, sigma-permuted)
  float* cosT = (float*)(ws + 150994944);         // 256KB
  float* sinT = (float*)(ws + 151257088);         // 256KB
  float* part = (float*)(ws + 151519232);         // 128KB
  float* meanb = (float*)(ws + 151650304);        //  16KB
  float* lwbuf = (float*)(ws + 151666688);        //  256B
  bf16* Qbf = hs_bf;
  bf16* Obuf = prev_bf;          // prev_bf dead after gemm_kv
  bf16* comb = (bf16*)(ws + 0);  // Qbf dead after attn

  // 1) dtype conversions
  cvt_kernel<<<4096, 256, 0, stream>>>(hs, hs_bf, 2048 * 2048 / 4);
  cvt_kernel<<<16384, 256, 0, stream>>>(prev, prev_bf, 8192 * 2048 / 4);

  // 2) weight transposes (fp32 -> bf16 [N][K])
  twt_kernel<<<dim3(32, 32), 256, 0, stream>>>(Wq, WqT);
  twt_kernel<<<dim3(32, 32), 256, 0, stream>>>(Wk, WkT);
  twt_kernel<<<dim3(32, 32), 256, 0, stream>>>(Wv, WvT);
  twt_kernel<<<dim3(32, 32), 256, 0, stream>>>(Wo, WoT);

  // 3) RoPE tables + gate
  rope_table_kernel<<<1024, 64, 0, stream>>>(cosT, sinT);
  mean_part_kernel<<<dim3(16, 8), 256, 0, stream>>>(hs, part);
  mean_fin_kernel<<<16, 256, 0, stream>>>(part, meanb);
  gate_kernel<<<1, 256, 0, stream>>>(meanb, Wg, lwbuf);

  // 4) projections: Q via 128^2; K+V fused 8-phase (K comes out rope'd)
  gemm_kernel<3><<<dim3(16, 16), 256, 0, stream>>>(hs_bf, WqT, bq, Qraw2, 2048, 2048, 2048);
  gemm_kv_kernel<<<512, 512, 0, stream>>>(prev_bf, WkT, WvT, bk, bv, cosT, sinT,
                                          Kbf, Vt);

  // 5) RoPE for Q only (K rope fused into gemm_kv epilogue)
  rope_kernel<<<2048, 256, 0, stream>>>(Qraw2, cosT, sinT, Qbf);

  // 6) attention: 128 q-rows per block, dbuf K/V (R10 structure)
  attn_kernel<<<dim3(32, 8, 4), 256, 0, stream>>>(Qbf, Kbf, Vt, lwbuf, Obuf);

  // 7) combine layers
  comb_kernel<<<2048, 256, 0, stream>>>(Obuf, comb);

  // 8) output projection -> fp32 d_out
  gemm_kernel<1><<<dim3(16, 16), 256, 0, stream>>>(comb, WoT, bo, out, 2048, 2048, 2048);
}

// Round 15
// 352.746 us; speedup vs baseline: 1.0692x; 1.0692x over previous
//
#include <hip/hip_runtime.h>
#include <hip/hip_bf16.h>
#include <math.h>

// ---------------------------------------------------------------------------
// MultiLayerAttention on MI355X (gfx950)
// B=2 S=1024 H=2048 NH=16 HD=128 L=4, fp32 in/out, bf16 MFMA internally.
// R15: gemm_kv = R12 main loop + R12 scattered epilogues (148us proven),
// with RoPE-K fused IN-REGISTER: WkT B-rows permuted at load (position p
// holds feature dmap(p) = {r, r+64, r+32, r+96}[p>>5], r=p&31) so rope
// partners (d, d+64) sit in acc[m][n] / acc[m][n+2] of the same lane.
// K epilogue applies rope on f32 acc+bias, stores R12's 32B pattern to the
// TRUE feature positions. rope-K kernel deleted. Attn = R10. R14's two-pass
// LDS epilogue reverted (+21us pipeline cost > RMW savings).
// ---------------------------------------------------------------------------

typedef __bf16 bf16;
typedef __bf16 bf16x4v __attribute__((ext_vector_type(4)));
typedef __bf16 bf16x8 __attribute__((ext_vector_type(8)));
typedef float f32x4 __attribute__((ext_vector_type(4)));

#define DEV static __device__ __forceinline__

DEV void gload_lds16(const void* g, void* s) {
  __builtin_amdgcn_global_load_lds(
      (const __attribute__((address_space(1))) void*)g,
      (__attribute__((address_space(3))) void*)s, 16, 0, 0);
}

DEV f32x4 mfma16(bf16x8 a, bf16x8 b, f32x4 c) {
  return __builtin_amdgcn_mfma_f32_16x16x32_bf16(a, b, c, 0, 0, 0);
}

// ---------------- fp32 -> bf16 conversion (vectorized) ----------------
__global__ __launch_bounds__(256) void cvt_kernel(const float* __restrict__ in,
                                                  bf16* __restrict__ out, int n4) {
  int i = blockIdx.x * 256 + threadIdx.x;
  if (i >= n4) return;
  const float4 v = ((const float4*)in)[i];
  bf16x4v o;
  o.x = (bf16)v.x; o.y = (bf16)v.y; o.z = (bf16)v.z; o.w = (bf16)v.w;
  ((bf16x4v*)out)[i] = o;
}

// ---------------- W [K=2048][N=2048] fp32 -> Wt [N][K] bf16 ----------------
__global__ __launch_bounds__(256) void twt_kernel(const float* __restrict__ W,
                                                  bf16* __restrict__ Wt) {
  __shared__ float tile[64][65];
  const int t = threadIdx.x;
  const int n0 = blockIdx.x * 64, k0 = blockIdx.y * 64;
#pragma unroll
  for (int ph = 0; ph < 16; ++ph) {
    int idx = ph * 256 + t, r = idx >> 6, c = idx & 63;
    tile[r][c] = W[(size_t)(k0 + r) * 2048 + n0 + c];
  }
  __syncthreads();
#pragma unroll
  for (int ph = 0; ph < 16; ++ph) {
    int idx = ph * 256 + t, r = idx >> 6, c = idx & 63;
    Wt[(size_t)(n0 + r) * 2048 + k0 + c] = (bf16)tile[c][r];
  }
}

// ---------------- RoPE tables ----------------
__global__ __launch_bounds__(64) void rope_table_kernel(float* __restrict__ cosT,
                                                        float* __restrict__ sinT) {
  int s = blockIdx.x, j = threadIdx.x;
  float inv = powf(10000.0f, -(float)j * (1.0f / 64.0f));
  float a = (float)s * inv;
  cosT[s * 64 + j] = cosf(a);
  sinT[s * 64 + j] = sinf(a);
}

// ---------------- RoPE in head-major layout, vectorized (Q only) -----------
__global__ __launch_bounds__(256) void rope_kernel(const bf16* __restrict__ raw,
                                                   const float* __restrict__ cosT,
                                                   const float* __restrict__ sinT,
                                                   bf16* __restrict__ outp) {
  int rid = blockIdx.x * 16 + (threadIdx.x >> 4);
  int j = threadIdx.x & 15;  // d0 = 4*j
  int s = rid & 1023;
  const bf16* src = raw + (size_t)rid * 128 + 4 * j;
  bf16* dst = outp + (size_t)rid * 128 + 4 * j;
  bf16x4v x1 = *(const bf16x4v*)src;
  bf16x4v x2 = *(const bf16x4v*)(src + 64);
  f32x4 c = *(const f32x4*)(cosT + s * 64 + 4 * j);
  f32x4 sn = *(const f32x4*)(sinT + s * 64 + 4 * j);
  bf16x4v o1, o2;
#pragma unroll
  for (int k = 0; k < 4; ++k) {
    float a = (float)x1[k], b2 = (float)x2[k];
    o1[k] = (bf16)(a * c[k] - b2 * sn[k]);
    o2[k] = (bf16)(b2 * c[k] + a * sn[k]);
  }
  *(bf16x4v*)dst = o1;
  *(bf16x4v*)(dst + 64) = o2;
}

// ---------------- mean over S (two-stage, deterministic) ----------------
__global__ __launch_bounds__(256) void mean_part_kernel(const float* __restrict__ hs,
                                                        float* __restrict__ part) {
  int bc = blockIdx.x;                 // 0..15: b*8 + colchunk
  int b = bc >> 3, c0 = (bc & 7) * 256;
  int ss = blockIdx.y;                 // 0..7
  int col = c0 + threadIdx.x;
  float s = 0.f;
  for (int r = 0; r < 128; ++r)
    s += hs[((size_t)b * 1024 + ss * 128 + r) * 2048 + col];
  part[(size_t)ss * 4096 + b * 2048 + col] = s;
}

__global__ __launch_bounds__(256) void mean_fin_kernel(const float* __restrict__ part,
                                                       float* __restrict__ meanb) {
  int c = blockIdx.x * 256 + threadIdx.x;  // 0..4095
  float s = 0.f;
#pragma unroll
  for (int j = 0; j < 8; ++j) s += part[(size_t)j * 4096 + c];
  meanb[c] = s * (1.0f / 1024.0f);
}

// ---------------- gate: softmax(mean @ Wg) -> layer_w[2][4] ----------------
__global__ __launch_bounds__(256) void gate_kernel(const float* __restrict__ meanb,
                                                   const float* __restrict__ Wg,
                                                   float* __restrict__ lwout) {
  __shared__ float red[8][256];
  int t = threadIdx.x;
  float p[8];
#pragma unroll
  for (int j = 0; j < 8; ++j) p[j] = 0.f;
  for (int hh = t; hh < 2048; hh += 256) {
    float m0 = meanb[hh], m1 = meanb[2048 + hh];
#pragma unroll
    for (int ll = 0; ll < 4; ++ll) {
      float g = Wg[hh * 4 + ll];
      p[ll] += m0 * g;
      p[4 + ll] += m1 * g;
    }
  }
#pragma unroll
  for (int j = 0; j < 8; ++j) red[j][t] = p[j];
  __syncthreads();
  for (int s2 = 128; s2 > 0; s2 >>= 1) {
    if (t < s2) {
#pragma unroll
      for (int j = 0; j < 8; ++j) red[j][t] += red[j][t + s2];
    }
    __syncthreads();
  }
  if (t == 0) {
#pragma unroll
    for (int bb = 0; bb < 2; ++bb) {
      float v0 = red[bb * 4 + 0][0], v1 = red[bb * 4 + 1][0];
      float v2 = red[bb * 4 + 2][0], v3 = red[bb * 4 + 3][0];
      float mx = fmaxf(fmaxf(v0, v1), fmaxf(v2, v3));
      float e0 = __expf(v0 - mx), e1 = __expf(v1 - mx);
      float e2 = __expf(v2 - mx), e3 = __expf(v3 - mx);
      float inv = 1.0f / (e0 + e1 + e2 + e3);
      lwout[bb * 4 + 0] = e0 * inv;
      lwout[bb * 4 + 1] = e1 * inv;
      lwout[bb * 4 + 2] = e2 * inv;
      lwout[bb * 4 + 3] = e3 * inv;
    }
  }
}

// ---------------- GEMM (128^2): C = A[M][K] @ Bt[N][K]^T + bias -------------
// Used for Q (OUTMODE 3) and O (OUTMODE 1) projections only.
template <int OUTMODE>
__global__ __launch_bounds__(256) void gemm_kernel(const bf16* __restrict__ A,
                                                   const bf16* __restrict__ Bt,
                                                   const float* __restrict__ bias,
                                                   void* __restrict__ Cout,
                                                   int M, int N, int K) {
  __shared__ __attribute__((aligned(16))) bf16 As[2][128 * 64];
  __shared__ __attribute__((aligned(16))) bf16 Bs[2][128 * 64];
  const int t = threadIdx.x;
  const int w = t >> 6, l = t & 63;
  const int lo = l & 15, hi = l >> 4;
  const int wr = w >> 1, wc = w & 1;

  const int nwg = gridDim.x * gridDim.y;
  int flat = blockIdx.y * gridDim.x + blockIdx.x;
  int swz = (flat & 7) * (nwg >> 3) + (flat >> 3);
  const int bx = swz % gridDim.x, by = swz / gridDim.x;

  f32x4 acc[4][4];
#pragma unroll
  for (int m = 0; m < 4; ++m)
#pragma unroll
    for (int n = 0; n < 4; ++n)
#pragma unroll
      for (int q = 0; q < 4; ++q) acc[m][n][q] = 0.f;

  int srow[4], scl[4];
#pragma unroll
  for (int p = 0; p < 4; ++p) {
    int id = p * 256 + t;
    int r = id >> 3, cph = id & 7;
    srow[p] = r;
    scl[p] = cph ^ (r & 7);
  }

  const bf16* Ab = A + (size_t)by * 128 * K;
  const bf16* Bb = Bt + (size_t)bx * 128 * K;

  auto stage = [&](int bi, int kt) {
#pragma unroll
    for (int p = 0; p < 4; ++p)
      gload_lds16(Ab + (size_t)srow[p] * K + kt + scl[p] * 8,
                  &As[bi][(p * 256 + w * 64) * 8]);
#pragma unroll
    for (int p = 0; p < 4; ++p)
      gload_lds16(Bb + (size_t)srow[p] * K + kt + scl[p] * 8,
                  &Bs[bi][(p * 256 + w * 64) * 8]);
  };

  stage(0, 0);
  int cur = 0;
  for (int kt = 0; kt < K; kt += 64) {
    if (kt + 64 < K) {
      stage(cur ^ 1, kt + 64);
      asm volatile("s_waitcnt vmcnt(8)" ::: "memory");
    } else {
      asm volatile("s_waitcnt vmcnt(0)" ::: "memory");
    }
    __builtin_amdgcn_s_barrier();
    __builtin_amdgcn_sched_barrier(0);
    __builtin_amdgcn_s_setprio(1);
#pragma unroll
    for (int ks = 0; ks < 2; ++ks) {
      bf16x8 af[4], bfr[4];
#pragma unroll
      for (int m = 0; m < 4; ++m) {
        int row = wr * 64 + m * 16 + lo;
        int ch = (ks * 4 + hi) ^ (row & 7);
        af[m] = *(const bf16x8*)&As[cur][row * 64 + ch * 8];
      }
#pragma unroll
      for (int n = 0; n < 4; ++n) {
        int row = wc * 64 + n * 16 + lo;
        int ch = (ks * 4 + hi) ^ (row & 7);
        bfr[n] = *(const bf16x8*)&Bs[cur][row * 64 + ch * 8];
      }
#pragma unroll
      for (int m = 0; m < 4; ++m)
#pragma unroll
        for (int n = 0; n < 4; ++n)
          acc[m][n] = mfma16(af[m], bfr[n], acc[m][n]);
    }
    __builtin_amdgcn_s_setprio(0);
    __builtin_amdgcn_s_barrier();
    cur ^= 1;
  }

#pragma unroll
  for (int n = 0; n < 4; ++n) {
    int col = bx * 128 + wc * 64 + n * 16 + lo;
    float bb = bias[col];
#pragma unroll
    for (int m = 0; m < 4; ++m) {
#pragma unroll
      for (int i = 0; i < 4; ++i) {
        size_t row = (size_t)by * 128 + wr * 64 + m * 16 + hi * 4 + i;
        float v = acc[m][n][i] + bb;
        if (OUTMODE == 1)
          ((float*)Cout)[row * N + col] = v;
        else if (OUTMODE == 0)
          ((bf16*)Cout)[row * N + col] = (bf16)v;
        else {  // 3: head-major
          size_t g = (row >> 10) * 16 + (col >> 7);
          ((bf16*)Cout)[(g * 1024 + (row & 1023)) * 128 + (col & 127)] = (bf16)v;
        }
      }
    }
  }
}

// ---------------- fused K+V projection GEMM, 256^2 tile, 8-phase ------------
// Main loop = R12. grp==0 (K): B-rows (WkT features) loaded PERMUTED so
// position p in each 128-block holds feature dmap(p) ({r,r+64,r+32,r+96},
// a=p>>5, r=p&31). Then acc[m][n] / acc[m][n+2] hold rope partners (d,d+64)
// in the SAME lane -> rope fused in-register in the scattered epilogue
// (stores to TRUE feature positions, R12's 32B store pattern).
__global__ __launch_bounds__(512, 2) void gemm_kv_kernel(
    const bf16* __restrict__ prev, const bf16* __restrict__ WkT,
    const bf16* __restrict__ WvT, const float* __restrict__ bk,
    const float* __restrict__ bv, const float* __restrict__ cosT,
    const float* __restrict__ sinT, bf16* __restrict__ Kout,
    bf16* __restrict__ Vout) {
  __shared__ __attribute__((aligned(16))) bf16 As[2][16384];
  __shared__ __attribute__((aligned(16))) bf16 Bs[2][16384];
  const int t = threadIdx.x;
  const int w = t >> 6, l = t & 63;
  const int lo = l & 15, hi = l >> 4;
  const int wm = w >> 2, wn = w & 3;

  const int bid = blockIdx.x;
  const int grp = bid >> 8;   // 0: K = prev(M) x WkT(N); 1: V^T = WvT(M) x prev(N)
  const int sub = bid & 255;
  const int swz = (sub & 7) * 32 + (sub >> 3);
  const int mt = (grp == 0) ? (swz >> 3) : (swz & 7);
  const int nt = (grp == 0) ? (swz & 7) : (swz >> 3);
  const bf16* Ab = ((grp == 0) ? prev : WvT) + (size_t)mt * 256 * 2048;
  const bf16* Bb = ((grp == 0) ? WkT : prev) + (size_t)nt * 256 * 2048;

  const int r0 = t >> 2;
  const int c8 = ((t & 3) ^ ((r0 >> 1) & 3)) * 8;
  // permuted B-row for K group: position r0 loads feature dmap(r0)
  int r0B = r0;
  if (grp == 0) {
    int a = r0 >> 5, rr = r0 & 31;
    r0B = (a == 0) ? rr : (a == 1) ? rr + 64 : (a == 2) ? rr + 32 : rr + 96;
  }

  f32x4 acc[8][4];
#pragma unroll
  for (int m = 0; m < 8; ++m)
#pragma unroll
    for (int n = 0; n < 4; ++n)
#pragma unroll
      for (int q = 0; q < 4; ++q) acc[m][n][q] = 0.f;

  auto gA = [&](int bi, int kh, int p, int koff) {
    gload_lds16(Ab + (size_t)(p * 128 + r0) * 2048 + koff + kh * 32 + c8,
                &As[bi][kh * 8192 + p * 4096 + w * 512]);
  };
  auto gB = [&](int bi, int kh, int p, int koff) {
    gload_lds16(Bb + (size_t)(p * 128 + r0B) * 2048 + koff + kh * 32 + c8,
                &Bs[bi][kh * 8192 + p * 4096 + w * 512]);
  };

  gA(0, 0, 0, 0); gA(0, 0, 1, 0);
  gB(0, 0, 0, 0); gB(0, 0, 1, 0);
  gA(0, 1, 0, 0); gA(0, 1, 1, 0);
  gB(0, 1, 0, 0); gB(0, 1, 1, 0);
  asm volatile("s_waitcnt vmcnt(4)" ::: "memory");
  __builtin_amdgcn_s_barrier();

  int cur = 0;
  for (int kt = 0; kt < 32; ++kt) {
    const int nxt = cur ^ 1;
    const int koff = (kt + 1) * 64;
    const bool pf = kt < 31;
    bf16x8 af[8], bfr[2];

    // ---------- phase 0: ks=0, n {0,1} ----------
#pragma unroll
    for (int m = 0; m < 8; ++m) {
      int row = wm * 128 + m * 16 + lo;
      int slot = hi ^ ((row >> 1) & 3);
      af[m] = *(const bf16x8*)&As[cur][row * 32 + slot * 8];
    }
#pragma unroll
    for (int n = 0; n < 2; ++n) {
      int row = wn * 64 + n * 16 + lo;
      int slot = hi ^ ((row >> 1) & 3);
      bfr[n] = *(const bf16x8*)&Bs[cur][row * 32 + slot * 8];
    }
    if (pf) { gA(nxt, 0, 0, koff); gA(nxt, 0, 1, koff); }
    __builtin_amdgcn_s_barrier();
    __builtin_amdgcn_s_setprio(1);
#pragma unroll
    for (int m = 0; m < 8; ++m) {
      acc[m][0] = mfma16(af[m], bfr[0], acc[m][0]);
      acc[m][1] = mfma16(af[m], bfr[1], acc[m][1]);
    }
    __builtin_amdgcn_s_setprio(0);
    __builtin_amdgcn_s_barrier();

    // ---------- phase 1: ks=0, n {2,3} ----------
#pragma unroll
    for (int n = 0; n < 2; ++n) {
      int row = wn * 64 + (n + 2) * 16 + lo;
      int slot = hi ^ ((row >> 1) & 3);
      bfr[n] = *(const bf16x8*)&Bs[cur][row * 32 + slot * 8];
    }
    if (pf) {
      gB(nxt, 0, 0, koff); gB(nxt, 0, 1, koff);
      asm volatile("s_waitcnt vmcnt(4)" ::: "memory");
    } else {
      asm volatile("s_waitcnt vmcnt(0)" ::: "memory");
    }
    __builtin_amdgcn_s_barrier();
    __builtin_amdgcn_s_setprio(1);
#pragma unroll
    for (int m = 0; m < 8; ++m) {
      acc[m][2] = mfma16(af[m], bfr[0], acc[m][2]);
      acc[m][3] = mfma16(af[m], bfr[1], acc[m][3]);
    }
    __builtin_amdgcn_s_setprio(0);
    __builtin_amdgcn_s_barrier();

    // ---------- phase 2: ks=1, n {0,1} ----------
#pragma unroll
    for (int m = 0; m < 8; ++m) {
      int row = wm * 128 + m * 16 + lo;
      int slot = hi ^ ((row >> 1) & 3);
      af[m] = *(const bf16x8*)&As[cur][8192 + row * 32 + slot * 8];
    }
#pragma unroll
    for (int n = 0; n < 2; ++n) {
      int row = wn * 64 + n * 16 + lo;
      int slot = hi ^ ((row >> 1) & 3);
      bfr[n] = *(const bf16x8*)&Bs[cur][8192 + row * 32 + slot * 8];
    }
    if (pf) { gA(nxt, 1, 0, koff); gA(nxt, 1, 1, koff); }
    __builtin_amdgcn_s_barrier();
    __builtin_amdgcn_s_setprio(1);
#pragma unroll
    for (int m = 0; m < 8; ++m) {
      acc[m][0] = mfma16(af[m], bfr[0], acc[m][0]);
      acc[m][1] = mfma16(af[m], bfr[1], acc[m][1]);
    }
    __builtin_amdgcn_s_setprio(0);
    __builtin_amdgcn_s_barrier();

    // ---------- phase 3: ks=1, n {2,3} ----------
#pragma unroll
    for (int n = 0; n < 2; ++n) {
      int row = wn * 64 + (n + 2) * 16 + lo;
      int slot = hi ^ ((row >> 1) & 3);
      bfr[n] = *(const bf16x8*)&Bs[cur][8192 + row * 32 + slot * 8];
    }
    if (pf) {
      gB(nxt, 1, 0, koff); gB(nxt, 1, 1, koff);
      asm volatile("s_waitcnt vmcnt(4)" ::: "memory");
    } else {
      asm volatile("s_waitcnt vmcnt(0)" ::: "memory");
    }
    __builtin_amdgcn_s_barrier();
    __builtin_amdgcn_s_setprio(1);
#pragma unroll
    for (int m = 0; m < 8; ++m) {
      acc[m][2] = mfma16(af[m], bfr[0], acc[m][2]);
      acc[m][3] = mfma16(af[m], bfr[1], acc[m][3]);
    }
    __builtin_amdgcn_s_setprio(0);
    __builtin_amdgcn_s_barrier();

    cur = nxt;
  }

  if (grp == 0) {
    // K epilogue with in-register RoPE. headg = nt*2 + (wn>>1);
    // j = (wn&1)*32 + n*16 + lo (n in {0,1}); partner acc is n+2.
    const int headg = nt * 2 + (wn >> 1);
    const int jbase = (wn & 1) * 32;
#pragma unroll
    for (int n = 0; n < 2; ++n) {
      int j = jbase + n * 16 + lo;
      float bb1 = bk[headg * 128 + j];
      float bb2 = bk[headg * 128 + j + 64];
#pragma unroll
      for (int m = 0; m < 8; ++m) {
#pragma unroll
        for (int i = 0; i < 4; ++i) {
          size_t srow = (size_t)mt * 256 + wm * 128 + m * 16 + hi * 4 + i;
          int s_idx = (int)(srow & 1023);
          size_t g = (srow >> 10) * 16 + headg;
          float x1 = acc[m][n][i] + bb1;
          float x2 = acc[m][n + 2][i] + bb2;
          float cc = cosT[s_idx * 64 + j];
          float ss = sinT[s_idx * 64 + j];
          bf16* dst = Kout + (g * 1024 + s_idx) * 128;
          dst[j] = (bf16)(x1 * cc - x2 * ss);
          dst[j + 64] = (bf16)(x2 * cc + x1 * ss);
        }
      }
    }
  } else {
    // V epilogue (R12 verbatim): V^T sigma-permuted scattered stores
#pragma unroll
    for (int m = 0; m < 8; ++m) {
#pragma unroll
      for (int i = 0; i < 4; ++i) {
        size_t row = (size_t)mt * 256 + wm * 128 + m * 16 + hi * 4 + i;
        float rb = bv[row];
#pragma unroll
        for (int n = 0; n < 4; ++n) {
          int col = nt * 256 + wn * 64 + n * 16 + lo;
          int pos64 = ((n >> 1) << 5) + ((lo >> 2) << 3) + ((n & 1) << 2) + (lo & 3);
          int colp = (col & ~63) | pos64;
          float v = acc[m][n][i] + rb;
          Vout[(size_t)(colp >> 10) * 2097152 + row * 1024 + (colp & 1023)] =
              (bf16)v;
        }
      }
    }
  }
}

// ---------------- fused flash attention (R10 verbatim) ----------
// grid (B*NH=32, S/128=8, L=4), 256 threads (4 waves, 2 q-subtiles each).
__global__ __launch_bounds__(256, 2) void attn_kernel(const bf16* __restrict__ Q,
                                                      const bf16* __restrict__ Kb,
                                                      const bf16* __restrict__ Vt,
                                                      const float* __restrict__ lw,
                                                      bf16* __restrict__ Obuf) {
  __shared__ __attribute__((aligned(16))) bf16 Ks[2][64 * 128];
  __shared__ __attribute__((aligned(16))) bf16 Vs[2][128 * 64];
  const int t = threadIdx.x, w = t >> 6, l = t & 63;
  const int lo = l & 15, hi = l >> 4;
  const int bh = blockIdx.x;  // b*16+h
  const int qt = blockIdx.y;  // 128-row q tile
  const int li = blockIdx.z;
  const int b = bh >> 4, h = bh & 15;
  const float C2 = 0.08838834764831845f * 1.44269504f;
  const float M2 = 64.0f * C2;

  bf16x8 qf[2][4];
#pragma unroll
  for (int qs = 0; qs < 2; ++qs) {
    const bf16* qptr =
        Q + ((size_t)bh * 1024 + qt * 128 + w * 32 + qs * 16 + lo) * 128;
#pragma unroll
    for (int db = 0; db < 4; ++db)
      qf[qs][db] = *(const bf16x8*)(qptr + db * 32 + hi * 8);
  }

  int krow[4], kcl[4], vrow[4], vcl[4];
#pragma unroll
  for (int p = 0; p < 4; ++p) {
    int id = p * 256 + t;
    krow[p] = id >> 4;
    kcl[p] = (id & 15) ^ (krow[p] & 7);
    vrow[p] = id >> 3;
    vcl[p] = (id & 7) ^ (vrow[p] & 7);
  }

  const bf16* Kl = Kb + ((size_t)li * 32 + bh) * (size_t)131072;
  const bf16* Vl = Vt + ((size_t)li * 32 + bh) * (size_t)131072;

  float si0 = 0.f, si1 = 0.f;
  f32x4 oacc[2][8];
#pragma unroll
  for (int qs = 0; qs < 2; ++qs)
#pragma unroll
    for (int dc = 0; dc < 8; ++dc)
#pragma unroll
      for (int q = 0; q < 4; ++q) oacc[qs][dc][q] = 0.f;

  auto stage = [&](int bi, int kt2) {
    const bf16* Ksrc = Kl + (size_t)kt2 * 8192;
#pragma unroll
    for (int p = 0; p < 4; ++p)
      gload_lds16(Ksrc + (size_t)krow[p] * 128 + kcl[p] * 8,
                  &Ks[bi][(p * 256 + w * 64) * 8]);
#pragma unroll
    for (int p = 0; p < 4; ++p)
      gload_lds16(Vl + (size_t)vrow[p] * 1024 + kt2 * 64 + vcl[p] * 8,
                  &Vs[bi][(p * 256 + w * 64) * 8]);
  };

  auto softmax_step = [&](f32x4 (&sa)[4], float& si, bf16x8 (&pf2)[2]) {
    float rs = 0.f;
    bf16x4v pk[4];
#pragma unroll
    for (int kc = 0; kc < 4; ++kc) {
#pragma unroll
      for (int i = 0; i < 4; ++i) {
        float pf_ = __builtin_amdgcn_exp2f(fmaf(sa[kc][i], C2, -M2));
        rs += pf_;
        pk[kc][i] = (bf16)pf_;
      }
    }
    rs += __shfl_xor(rs, 16);
    rs += __shfl_xor(rs, 32);
    si += rs;
    pf2[0] = __builtin_shufflevector(pk[0], pk[1], 0, 1, 2, 3, 4, 5, 6, 7);
    pf2[1] = __builtin_shufflevector(pk[2], pk[3], 0, 1, 2, 3, 4, 5, 6, 7);
  };

  stage(0, 0);
  int cur = 0;
  for (int kt = 0; kt < 16; ++kt) {
    if (kt < 15) {
      stage(cur ^ 1, kt + 1);
      asm volatile("s_waitcnt vmcnt(8)" ::: "memory");
    } else {
      asm volatile("s_waitcnt vmcnt(0)" ::: "memory");
    }
    __builtin_amdgcn_s_barrier();
    __builtin_amdgcn_sched_barrier(0);

    f32x4 sa[2][4];
#pragma unroll
    for (int qs = 0; qs < 2; ++qs)
#pragma unroll
      for (int kc = 0; kc < 4; ++kc)
#pragma unroll
        for (int q = 0; q < 4; ++q) sa[qs][kc][q] = 0.f;
    __builtin_amdgcn_s_setprio(1);
#pragma unroll
    for (int kc = 0; kc < 4; ++kc) {
      int row = kc * 16 + lo;
#pragma unroll
      for (int db = 0; db < 4; ++db) {
        int ch = (db * 4 + hi) ^ (row & 7);
        bf16x8 kf = *(const bf16x8*)&Ks[cur][row * 128 + ch * 8];
        sa[0][kc] = mfma16(kf, qf[0][db], sa[0][kc]);
        sa[1][kc] = mfma16(kf, qf[1][db], sa[1][kc]);
      }
    }
    __builtin_amdgcn_s_setprio(0);

    bf16x8 pfr[2][2];
    softmax_step(sa[0], si0, pfr[0]);
    softmax_step(sa[1], si1, pfr[1]);

    __builtin_amdgcn_s_setprio(1);
#pragma unroll
    for (int kvc = 0; kvc < 2; ++kvc) {
#pragma unroll
      for (int dc = 0; dc < 8; ++dc) {
        int rowv = dc * 16 + lo;
        int ch = (kvc * 4 + hi) ^ (rowv & 7);
        bf16x8 vf = *(const bf16x8*)&Vs[cur][rowv * 64 + ch * 8];
        oacc[0][dc] = mfma16(pfr[0][kvc], vf, oacc[0][dc]);
        oacc[1][dc] = mfma16(pfr[1][kvc], vf, oacc[1][dc]);
      }
    }
    __builtin_amdgcn_s_setprio(0);
    __builtin_amdgcn_s_barrier();
    cur ^= 1;
  }

  float wl = lw[b * 4 + li];
#pragma unroll
  for (int qs = 0; qs < 2; ++qs) {
    float sv = (qs == 0) ? si0 : si1;
    float inv[4];
#pragma unroll
    for (int i = 0; i < 4; ++i) inv[i] = wl / __shfl(sv, hi * 4 + i);
#pragma unroll
    for (int dc = 0; dc < 8; ++dc) {
      int col = h * 128 + dc * 16 + lo;
#pragma unroll
      for (int i = 0; i < 4; ++i) {
        int srow = qt * 128 + w * 32 + qs * 16 + hi * 4 + i;
        Obuf[((size_t)(li * 2 + b) * 1024 + srow) * 2048 + col] =
            (bf16)(oacc[qs][dc][i] * inv[i]);
      }
    }
  }
}

// ---------------- layer combine: comb = sum_l Obuf[l] ----------------
__global__ __launch_bounds__(256) void comb_kernel(const bf16* __restrict__ Obuf,
                                                   bf16* __restrict__ comb) {
  size_t i = ((size_t)blockIdx.x * 256 + threadIdx.x) * 8;
  bf16x8 a0 = *(const bf16x8*)(Obuf + i);
  bf16x8 a1 = *(const bf16x8*)(Obuf + 4194304 + i);
  bf16x8 a2 = *(const bf16x8*)(Obuf + 8388608 + i);
  bf16x8 a3 = *(const bf16x8*)(Obuf + 12582912 + i);
  bf16x8 o;
#pragma unroll
  for (int j = 0; j < 8; ++j)
    o[j] = (bf16)((float)a0[j] + (float)a1[j] + (float)a2[j] + (float)a3[j]);
  *(bf16x8*)(comb + i) = o;
}

// ---------------------------------------------------------------------------
extern "C" void kernel_launch(void* const* d_in, const int* in_sizes, int n_in,
                              void* d_out, int out_size, void* d_ws, size_t ws_size,
                              hipStream_t stream) {
  (void)in_sizes; (void)n_in; (void)out_size; (void)ws_size;
  const float* hs = (const float*)d_in[0];     // [2,1024,2048]
  const float* prev = (const float*)d_in[1];   // [4,2,1024,2048]
  const float* Wq = (const float*)d_in[2];
  const float* bq = (const float*)d_in[3];
  const float* Wk = (const float*)d_in[4];
  const float* bk = (const float*)d_in[5];
  const float* Wv = (const float*)d_in[6];
  const float* bv = (const float*)d_in[7];
  const float* Wo = (const float*)d_in[8];
  const float* bo = (const float*)d_in[9];
  const float* Wg = (const float*)d_in[10];
  float* out = (float*)d_out;

  char* ws = (char*)d_ws;
  bf16* hs_bf = (bf16*)(ws + 0);                  //  8MB ; later Qbf, then comb
  bf16* prev_bf = (bf16*)(ws + 8388608);          // 32MB ; later Obuf
  bf16* WqT = (bf16*)(ws + 41943040);             //  8MB
  bf16* WkT = (bf16*)(ws + 50331648);             //  8MB
  bf16* WvT = (bf16*)(ws + 58720256);             //  8MB
  bf16* Qraw2 = (bf16*)(ws + 67108864);           //  8MB (head-major Q)
  bf16* WoT = (bf16*)(ws + 75497472);             //  8MB
  bf16* Kbf = (bf16*)(ws + 83886080);             // 32MB final rope'd K (from gemm_kv)
  bf16* Vt = (bf16*)(ws + 117440512);             // 32MB (V^T, sigma-permuted)
  float* cosT = (float*)(ws + 150994944);         // 256KB
  float* sinT = (float*)(ws + 151257088);         // 256KB
  float* part = (float*)(ws + 151519232);         // 128KB
  float* meanb = (float*)(ws + 151650304);        //  16KB
  float* lwbuf = (float*)(ws + 151666688);        //  256B
  bf16* Qbf = hs_bf;
  bf16* Obuf = prev_bf;          // prev_bf dead after gemm_kv
  bf16* comb = (bf16*)(ws + 0);  // Qbf dead after attn

  // 1) dtype conversions
  cvt_kernel<<<4096, 256, 0, stream>>>(hs, hs_bf, 2048 * 2048 / 4);
  cvt_kernel<<<16384, 256, 0, stream>>>(prev, prev_bf, 8192 * 2048 / 4);

  // 2) weight transposes (fp32 -> bf16 [N][K])
  twt_kernel<<<dim3(32, 32), 256, 0, stream>>>(Wq, WqT);
  twt_kernel<<<dim3(32, 32), 256, 0, stream>>>(Wk, WkT);
  twt_kernel<<<dim3(32, 32), 256, 0, stream>>>(Wv, WvT);
  twt_kernel<<<dim3(32, 32), 256, 0, stream>>>(Wo, WoT);

  // 3) RoPE tables + gate
  rope_table_kernel<<<1024, 64, 0, stream>>>(cosT, sinT);
  mean_part_kernel<<<dim3(16, 8), 256, 0, stream>>>(hs, part);
  mean_fin_kernel<<<16, 256, 0, stream>>>(part, meanb);
  gate_kernel<<<1, 256, 0, stream>>>(meanb, Wg, lwbuf);

  // 4) projections: Q via 128^2; K+V fused 8-phase (K comes out rope'd)
  gemm_kernel<3><<<dim3(16, 16), 256, 0, stream>>>(hs_bf, WqT, bq, Qraw2, 2048, 2048, 2048);
  gemm_kv_kernel<<<512, 512, 0, stream>>>(prev_bf, WkT, WvT, bk, bv, cosT, sinT,
                                          Kbf, Vt);

  // 5) RoPE for Q only (K rope fused into gemm_kv epilogue)
  rope_kernel<<<2048, 256, 0, stream>>>(Qraw2, cosT, sinT, Qbf);

  // 6) attention: 128 q-rows per block, dbuf K/V (R10 structure)
  attn_kernel<<<dim3(32, 8, 4), 256, 0, stream>>>(Qbf, Kbf, Vt, lwbuf, Obuf);

  // 7) combine layers
  comb_kernel<<<2048, 256, 0, stream>>>(Obuf, comb);

  // 8) output projection -> fp32 d_out
  gemm_kernel<1><<<dim3(16, 16), 256, 0, stream>>>(comb, WoT, bo, out, 2048, 2048, 2048);
}

// Round 16
// 338.218 us; speedup vs baseline: 1.1152x; 1.0430x over previous
//
#include <hip/hip_runtime.h>
#include <hip/hip_bf16.h>
#include <math.h>

// ---------------------------------------------------------------------------
// MultiLayerAttention on MI355X (gfx950)
// B=2 S=1024 H=2048 NH=16 HD=128 L=4, fp32 in/out, bf16 MFMA internally.
// R16: (1) attn softmax denominator computed by MFMA-with-ones B-fragment
// (accumulates si in C-layout matching the epilogue -> deletes per-tile adds
// + all denominator shuffles; VALU->MFMA shift on a VALU-bound kernel).
// (2) rope-Q fused into Q-GEMM via R15's verified dmap B-permutation
// (OUTMODE 4; rope_kernel deleted). (3) 4 twt launches merged into one.
// gemm_kv = R15 (147us, rope-K fused). attn structure = R10.
// ---------------------------------------------------------------------------

typedef __bf16 bf16;
typedef __bf16 bf16x4v __attribute__((ext_vector_type(4)));
typedef __bf16 bf16x8 __attribute__((ext_vector_type(8)));
typedef float f32x4 __attribute__((ext_vector_type(4)));

#define DEV static __device__ __forceinline__

DEV void gload_lds16(const void* g, void* s) {
  __builtin_amdgcn_global_load_lds(
      (const __attribute__((address_space(1))) void*)g,
      (__attribute__((address_space(3))) void*)s, 16, 0, 0);
}

DEV f32x4 mfma16(bf16x8 a, bf16x8 b, f32x4 c) {
  return __builtin_amdgcn_mfma_f32_16x16x32_bf16(a, b, c, 0, 0, 0);
}

// ---------------- fp32 -> bf16 conversion (vectorized) ----------------
__global__ __launch_bounds__(256) void cvt_kernel(const float* __restrict__ in,
                                                  bf16* __restrict__ out, int n4) {
  int i = blockIdx.x * 256 + threadIdx.x;
  if (i >= n4) return;
  const float4 v = ((const float4*)in)[i];
  bf16x4v o;
  o.x = (bf16)v.x; o.y = (bf16)v.y; o.z = (bf16)v.z; o.w = (bf16)v.w;
  ((bf16x4v*)out)[i] = o;
}

// ---------------- 4x W [K][N] fp32 -> Wt [N][K] bf16 (one launch) ----------
__global__ __launch_bounds__(256) void twt4_kernel(
    const float* __restrict__ W0, const float* __restrict__ W1,
    const float* __restrict__ W2, const float* __restrict__ W3,
    bf16* __restrict__ T0, bf16* __restrict__ T1, bf16* __restrict__ T2,
    bf16* __restrict__ T3) {
  const float* W = (blockIdx.z == 0) ? W0 : (blockIdx.z == 1) ? W1
                    : (blockIdx.z == 2) ? W2 : W3;
  bf16* Wt = (blockIdx.z == 0) ? T0 : (blockIdx.z == 1) ? T1
              : (blockIdx.z == 2) ? T2 : T3;
  __shared__ float tile[64][65];
  const int t = threadIdx.x;
  const int n0 = blockIdx.x * 64, k0 = blockIdx.y * 64;
#pragma unroll
  for (int ph = 0; ph < 16; ++ph) {
    int idx = ph * 256 + t, r = idx >> 6, c = idx & 63;
    tile[r][c] = W[(size_t)(k0 + r) * 2048 + n0 + c];
  }
  __syncthreads();
#pragma unroll
  for (int ph = 0; ph < 16; ++ph) {
    int idx = ph * 256 + t, r = idx >> 6, c = idx & 63;
    Wt[(size_t)(n0 + r) * 2048 + k0 + c] = (bf16)tile[c][r];
  }
}

// ---------------- RoPE tables ----------------
__global__ __launch_bounds__(64) void rope_table_kernel(float* __restrict__ cosT,
                                                        float* __restrict__ sinT) {
  int s = blockIdx.x, j = threadIdx.x;
  float inv = powf(10000.0f, -(float)j * (1.0f / 64.0f));
  float a = (float)s * inv;
  cosT[s * 64 + j] = cosf(a);
  sinT[s * 64 + j] = sinf(a);
}

// ---------------- mean over S (two-stage, deterministic) ----------------
__global__ __launch_bounds__(256) void mean_part_kernel(const float* __restrict__ hs,
                                                        float* __restrict__ part) {
  int bc = blockIdx.x;                 // 0..15: b*8 + colchunk
  int b = bc >> 3, c0 = (bc & 7) * 256;
  int ss = blockIdx.y;                 // 0..7
  int col = c0 + threadIdx.x;
  float s = 0.f;
  for (int r = 0; r < 128; ++r)
    s += hs[((size_t)b * 1024 + ss * 128 + r) * 2048 + col];
  part[(size_t)ss * 4096 + b * 2048 + col] = s;
}

__global__ __launch_bounds__(256) void mean_fin_kernel(const float* __restrict__ part,
                                                       float* __restrict__ meanb) {
  int c = blockIdx.x * 256 + threadIdx.x;  // 0..4095
  float s = 0.f;
#pragma unroll
  for (int j = 0; j < 8; ++j) s += part[(size_t)j * 4096 + c];
  meanb[c] = s * (1.0f / 1024.0f);
}

// ---------------- gate: softmax(mean @ Wg) -> layer_w[2][4] ----------------
__global__ __launch_bounds__(256) void gate_kernel(const float* __restrict__ meanb,
                                                   const float* __restrict__ Wg,
                                                   float* __restrict__ lwout) {
  __shared__ float red[8][256];
  int t = threadIdx.x;
  float p[8];
#pragma unroll
  for (int j = 0; j < 8; ++j) p[j] = 0.f;
  for (int hh = t; hh < 2048; hh += 256) {
    float m0 = meanb[hh], m1 = meanb[2048 + hh];
#pragma unroll
    for (int ll = 0; ll < 4; ++ll) {
      float g = Wg[hh * 4 + ll];
      p[ll] += m0 * g;
      p[4 + ll] += m1 * g;
    }
  }
#pragma unroll
  for (int j = 0; j < 8; ++j) red[j][t] = p[j];
  __syncthreads();
  for (int s2 = 128; s2 > 0; s2 >>= 1) {
    if (t < s2) {
#pragma unroll
      for (int j = 0; j < 8; ++j) red[j][t] += red[j][t + s2];
    }
    __syncthreads();
  }
  if (t == 0) {
#pragma unroll
    for (int bb = 0; bb < 2; ++bb) {
      float v0 = red[bb * 4 + 0][0], v1 = red[bb * 4 + 1][0];
      float v2 = red[bb * 4 + 2][0], v3 = red[bb * 4 + 3][0];
      float mx = fmaxf(fmaxf(v0, v1), fmaxf(v2, v3));
      float e0 = __expf(v0 - mx), e1 = __expf(v1 - mx);
      float e2 = __expf(v2 - mx), e3 = __expf(v3 - mx);
      float inv = 1.0f / (e0 + e1 + e2 + e3);
      lwout[bb * 4 + 0] = e0 * inv;
      lwout[bb * 4 + 1] = e1 * inv;
      lwout[bb * 4 + 2] = e2 * inv;
      lwout[bb * 4 + 3] = e3 * inv;
    }
  }
}

// ---------------- GEMM (128^2): C = A[M][K] @ Bt[N][K]^T + bias -------------
// OUTMODE 1: f32 C[row*N+col] (O-projection)
// OUTMODE 4: Q-projection with fused RoPE: Bt rows permuted at load via
//   dmap (position p holds feature {r,r+64,r+32,r+96}[p>>5], r=p&31);
//   epilogue applies rope on f32 acc+bias and writes head-major
//   [g=(row>>10)*16+bx][row&1023][d]. head = bx (128 cols per N-tile).
template <int OUTMODE>
__global__ __launch_bounds__(256) void gemm_kernel(const bf16* __restrict__ A,
                                                   const bf16* __restrict__ Bt,
                                                   const float* __restrict__ bias,
                                                   void* __restrict__ Cout,
                                                   int M, int N, int K,
                                                   const float* __restrict__ cosT,
                                                   const float* __restrict__ sinT) {
  __shared__ __attribute__((aligned(16))) bf16 As[2][128 * 64];
  __shared__ __attribute__((aligned(16))) bf16 Bs[2][128 * 64];
  const int t = threadIdx.x;
  const int w = t >> 6, l = t & 63;
  const int lo = l & 15, hi = l >> 4;
  const int wr = w >> 1, wc = w & 1;

  const int nwg = gridDim.x * gridDim.y;
  int flat = blockIdx.y * gridDim.x + blockIdx.x;
  int swz = (flat & 7) * (nwg >> 3) + (flat >> 3);
  const int bx = swz % gridDim.x, by = swz / gridDim.x;

  f32x4 acc[4][4];
#pragma unroll
  for (int m = 0; m < 4; ++m)
#pragma unroll
    for (int n = 0; n < 4; ++n)
#pragma unroll
      for (int q = 0; q < 4; ++q) acc[m][n][q] = 0.f;

  int srow[4], scl[4], srowB[4];
#pragma unroll
  for (int p = 0; p < 4; ++p) {
    int id = p * 256 + t;
    int r = id >> 3, cph = id & 7;
    srow[p] = r;
    scl[p] = cph ^ (r & 7);
    srowB[p] = r;
    if (OUTMODE == 4) {
      int a = r >> 5, rr = r & 31;
      srowB[p] = (a == 0) ? rr : (a == 1) ? rr + 64 : (a == 2) ? rr + 32 : rr + 96;
    }
  }

  const bf16* Ab = A + (size_t)by * 128 * K;
  const bf16* Bb = Bt + (size_t)bx * 128 * K;

  auto stage = [&](int bi, int kt) {
#pragma unroll
    for (int p = 0; p < 4; ++p)
      gload_lds16(Ab + (size_t)srow[p] * K + kt + scl[p] * 8,
                  &As[bi][(p * 256 + w * 64) * 8]);
#pragma unroll
    for (int p = 0; p < 4; ++p)
      gload_lds16(Bb + (size_t)srowB[p] * K + kt + scl[p] * 8,
                  &Bs[bi][(p * 256 + w * 64) * 8]);
  };

  stage(0, 0);
  int cur = 0;
  for (int kt = 0; kt < K; kt += 64) {
    if (kt + 64 < K) {
      stage(cur ^ 1, kt + 64);
      asm volatile("s_waitcnt vmcnt(8)" ::: "memory");
    } else {
      asm volatile("s_waitcnt vmcnt(0)" ::: "memory");
    }
    __builtin_amdgcn_s_barrier();
    __builtin_amdgcn_sched_barrier(0);
    __builtin_amdgcn_s_setprio(1);
#pragma unroll
    for (int ks = 0; ks < 2; ++ks) {
      bf16x8 af[4], bfr[4];
#pragma unroll
      for (int m = 0; m < 4; ++m) {
        int row = wr * 64 + m * 16 + lo;
        int ch = (ks * 4 + hi) ^ (row & 7);
        af[m] = *(const bf16x8*)&As[cur][row * 64 + ch * 8];
      }
#pragma unroll
      for (int n = 0; n < 4; ++n) {
        int row = wc * 64 + n * 16 + lo;
        int ch = (ks * 4 + hi) ^ (row & 7);
        bfr[n] = *(const bf16x8*)&Bs[cur][row * 64 + ch * 8];
      }
#pragma unroll
      for (int m = 0; m < 4; ++m)
#pragma unroll
        for (int n = 0; n < 4; ++n)
          acc[m][n] = mfma16(af[m], bfr[n], acc[m][n]);
    }
    __builtin_amdgcn_s_setprio(0);
    __builtin_amdgcn_s_barrier();
    cur ^= 1;
  }

  if (OUTMODE == 4) {
    // fused-rope Q epilogue: head = bx; j = wc*32 + n*16 + lo, partner n+2
    const int jb = wc * 32;
#pragma unroll
    for (int n = 0; n < 2; ++n) {
      int j = jb + n * 16 + lo;
      float bb1 = bias[bx * 128 + j];
      float bb2 = bias[bx * 128 + j + 64];
#pragma unroll
      for (int m = 0; m < 4; ++m) {
#pragma unroll
        for (int i = 0; i < 4; ++i) {
          size_t row = (size_t)by * 128 + wr * 64 + m * 16 + hi * 4 + i;
          int s_idx = (int)(row & 1023);
          size_t g = (row >> 10) * 16 + bx;
          float x1 = acc[m][n][i] + bb1;
          float x2 = acc[m][n + 2][i] + bb2;
          float cc = cosT[s_idx * 64 + j];
          float ss = sinT[s_idx * 64 + j];
          bf16* dst = (bf16*)Cout + (g * 1024 + s_idx) * 128;
          dst[j] = (bf16)(x1 * cc - x2 * ss);
          dst[j + 64] = (bf16)(x2 * cc + x1 * ss);
        }
      }
    }
  } else {
#pragma unroll
    for (int n = 0; n < 4; ++n) {
      int col = bx * 128 + wc * 64 + n * 16 + lo;
      float bb = bias[col];
#pragma unroll
      for (int m = 0; m < 4; ++m) {
#pragma unroll
        for (int i = 0; i < 4; ++i) {
          size_t row = (size_t)by * 128 + wr * 64 + m * 16 + hi * 4 + i;
          float v = acc[m][n][i] + bb;
          ((float*)Cout)[row * N + col] = v;
        }
      }
    }
  }
}

// ---------------- fused K+V projection GEMM, 256^2 tile, 8-phase ------------
// (R15 verbatim: R12 main loop + in-register rope-K + R12 V epilogue)
__global__ __launch_bounds__(512, 2) void gemm_kv_kernel(
    const bf16* __restrict__ prev, const bf16* __restrict__ WkT,
    const bf16* __restrict__ WvT, const float* __restrict__ bk,
    const float* __restrict__ bv, const float* __restrict__ cosT,
    const float* __restrict__ sinT, bf16* __restrict__ Kout,
    bf16* __restrict__ Vout) {
  __shared__ __attribute__((aligned(16))) bf16 As[2][16384];
  __shared__ __attribute__((aligned(16))) bf16 Bs[2][16384];
  const int t = threadIdx.x;
  const int w = t >> 6, l = t & 63;
  const int lo = l & 15, hi = l >> 4;
  const int wm = w >> 2, wn = w & 3;

  const int bid = blockIdx.x;
  const int grp = bid >> 8;
  const int sub = bid & 255;
  const int swz = (sub & 7) * 32 + (sub >> 3);
  const int mt = (grp == 0) ? (swz >> 3) : (swz & 7);
  const int nt = (grp == 0) ? (swz & 7) : (swz >> 3);
  const bf16* Ab = ((grp == 0) ? prev : WvT) + (size_t)mt * 256 * 2048;
  const bf16* Bb = ((grp == 0) ? WkT : prev) + (size_t)nt * 256 * 2048;

  const int r0 = t >> 2;
  const int c8 = ((t & 3) ^ ((r0 >> 1) & 3)) * 8;
  int r0B = r0;
  if (grp == 0) {
    int a = r0 >> 5, rr = r0 & 31;
    r0B = (a == 0) ? rr : (a == 1) ? rr + 64 : (a == 2) ? rr + 32 : rr + 96;
  }

  f32x4 acc[8][4];
#pragma unroll
  for (int m = 0; m < 8; ++m)
#pragma unroll
    for (int n = 0; n < 4; ++n)
#pragma unroll
      for (int q = 0; q < 4; ++q) acc[m][n][q] = 0.f;

  auto gA = [&](int bi, int kh, int p, int koff) {
    gload_lds16(Ab + (size_t)(p * 128 + r0) * 2048 + koff + kh * 32 + c8,
                &As[bi][kh * 8192 + p * 4096 + w * 512]);
  };
  auto gB = [&](int bi, int kh, int p, int koff) {
    gload_lds16(Bb + (size_t)(p * 128 + r0B) * 2048 + koff + kh * 32 + c8,
                &Bs[bi][kh * 8192 + p * 4096 + w * 512]);
  };

  gA(0, 0, 0, 0); gA(0, 0, 1, 0);
  gB(0, 0, 0, 0); gB(0, 0, 1, 0);
  gA(0, 1, 0, 0); gA(0, 1, 1, 0);
  gB(0, 1, 0, 0); gB(0, 1, 1, 0);
  asm volatile("s_waitcnt vmcnt(4)" ::: "memory");
  __builtin_amdgcn_s_barrier();

  int cur = 0;
  for (int kt = 0; kt < 32; ++kt) {
    const int nxt = cur ^ 1;
    const int koff = (kt + 1) * 64;
    const bool pf = kt < 31;
    bf16x8 af[8], bfr[2];

    // ---------- phase 0: ks=0, n {0,1} ----------
#pragma unroll
    for (int m = 0; m < 8; ++m) {
      int row = wm * 128 + m * 16 + lo;
      int slot = hi ^ ((row >> 1) & 3);
      af[m] = *(const bf16x8*)&As[cur][row * 32 + slot * 8];
    }
#pragma unroll
    for (int n = 0; n < 2; ++n) {
      int row = wn * 64 + n * 16 + lo;
      int slot = hi ^ ((row >> 1) & 3);
      bfr[n] = *(const bf16x8*)&Bs[cur][row * 32 + slot * 8];
    }
    if (pf) { gA(nxt, 0, 0, koff); gA(nxt, 0, 1, koff); }
    __builtin_amdgcn_s_barrier();
    __builtin_amdgcn_s_setprio(1);
#pragma unroll
    for (int m = 0; m < 8; ++m) {
      acc[m][0] = mfma16(af[m], bfr[0], acc[m][0]);
      acc[m][1] = mfma16(af[m], bfr[1], acc[m][1]);
    }
    __builtin_amdgcn_s_setprio(0);
    __builtin_amdgcn_s_barrier();

    // ---------- phase 1: ks=0, n {2,3} ----------
#pragma unroll
    for (int n = 0; n < 2; ++n) {
      int row = wn * 64 + (n + 2) * 16 + lo;
      int slot = hi ^ ((row >> 1) & 3);
      bfr[n] = *(const bf16x8*)&Bs[cur][row * 32 + slot * 8];
    }
    if (pf) {
      gB(nxt, 0, 0, koff); gB(nxt, 0, 1, koff);
      asm volatile("s_waitcnt vmcnt(4)" ::: "memory");
    } else {
      asm volatile("s_waitcnt vmcnt(0)" ::: "memory");
    }
    __builtin_amdgcn_s_barrier();
    __builtin_amdgcn_s_setprio(1);
#pragma unroll
    for (int m = 0; m < 8; ++m) {
      acc[m][2] = mfma16(af[m], bfr[0], acc[m][2]);
      acc[m][3] = mfma16(af[m], bfr[1], acc[m][3]);
    }
    __builtin_amdgcn_s_setprio(0);
    __builtin_amdgcn_s_barrier();

    // ---------- phase 2: ks=1, n {0,1} ----------
#pragma unroll
    for (int m = 0; m < 8; ++m) {
      int row = wm * 128 + m * 16 + lo;
      int slot = hi ^ ((row >> 1) & 3);
      af[m] = *(const bf16x8*)&As[cur][8192 + row * 32 + slot * 8];
    }
#pragma unroll
    for (int n = 0; n < 2; ++n) {
      int row = wn * 64 + n * 16 + lo;
      int slot = hi ^ ((row >> 1) & 3);
      bfr[n] = *(const bf16x8*)&Bs[cur][8192 + row * 32 + slot * 8];
    }
    if (pf) { gA(nxt, 1, 0, koff); gA(nxt, 1, 1, koff); }
    __builtin_amdgcn_s_barrier();
    __builtin_amdgcn_s_setprio(1);
#pragma unroll
    for (int m = 0; m < 8; ++m) {
      acc[m][0] = mfma16(af[m], bfr[0], acc[m][0]);
      acc[m][1] = mfma16(af[m], bfr[1], acc[m][1]);
    }
    __builtin_amdgcn_s_setprio(0);
    __builtin_amdgcn_s_barrier();

    // ---------- phase 3: ks=1, n {2,3} ----------
#pragma unroll
    for (int n = 0; n < 2; ++n) {
      int row = wn * 64 + (n + 2) * 16 + lo;
      int slot = hi ^ ((row >> 1) & 3);
      bfr[n] = *(const bf16x8*)&Bs[cur][8192 + row * 32 + slot * 8];
    }
    if (pf) {
      gB(nxt, 1, 0, koff); gB(nxt, 1, 1, koff);
      asm volatile("s_waitcnt vmcnt(4)" ::: "memory");
    } else {
      asm volatile("s_waitcnt vmcnt(0)" ::: "memory");
    }
    __builtin_amdgcn_s_barrier();
    __builtin_amdgcn_s_setprio(1);
#pragma unroll
    for (int m = 0; m < 8; ++m) {
      acc[m][2] = mfma16(af[m], bfr[0], acc[m][2]);
      acc[m][3] = mfma16(af[m], bfr[1], acc[m][3]);
    }
    __builtin_amdgcn_s_setprio(0);
    __builtin_amdgcn_s_barrier();

    cur = nxt;
  }

  if (grp == 0) {
    const int headg = nt * 2 + (wn >> 1);
    const int jbase = (wn & 1) * 32;
#pragma unroll
    for (int n = 0; n < 2; ++n) {
      int j = jbase + n * 16 + lo;
      float bb1 = bk[headg * 128 + j];
      float bb2 = bk[headg * 128 + j + 64];
#pragma unroll
      for (int m = 0; m < 8; ++m) {
#pragma unroll
        for (int i = 0; i < 4; ++i) {
          size_t srow = (size_t)mt * 256 + wm * 128 + m * 16 + hi * 4 + i;
          int s_idx = (int)(srow & 1023);
          size_t g = (srow >> 10) * 16 + headg;
          float x1 = acc[m][n][i] + bb1;
          float x2 = acc[m][n + 2][i] + bb2;
          float cc = cosT[s_idx * 64 + j];
          float ss = sinT[s_idx * 64 + j];
          bf16* dst = Kout + (g * 1024 + s_idx) * 128;
          dst[j] = (bf16)(x1 * cc - x2 * ss);
          dst[j + 64] = (bf16)(x2 * cc + x1 * ss);
        }
      }
    }
  } else {
#pragma unroll
    for (int m = 0; m < 8; ++m) {
#pragma unroll
      for (int i = 0; i < 4; ++i) {
        size_t row = (size_t)mt * 256 + wm * 128 + m * 16 + hi * 4 + i;
        float rb = bv[row];
#pragma unroll
        for (int n = 0; n < 4; ++n) {
          int col = nt * 256 + wn * 64 + n * 16 + lo;
          int pos64 = ((n >> 1) << 5) + ((lo >> 2) << 3) + ((n & 1) << 2) + (lo & 3);
          int colp = (col & ~63) | pos64;
          float v = acc[m][n][i] + rb;
          Vout[(size_t)(colp >> 10) * 2097152 + row * 1024 + (colp & 1023)] =
              (bf16)v;
        }
      }
    }
  }
}

// ---------------- fused flash attention (R10 + MFMA-ones denominator) ------
// grid (B*NH=32, S/128=8, L=4), 256 threads (4 waves, 2 q-subtiles each).
// Denominator si accumulated via mfma(P, ones) into dacc -- C-layout
// row=hi*4+i matches the output epilogue exactly (no shuffles).
__global__ __launch_bounds__(256, 2) void attn_kernel(const bf16* __restrict__ Q,
                                                      const bf16* __restrict__ Kb,
                                                      const bf16* __restrict__ Vt,
                                                      const float* __restrict__ lw,
                                                      bf16* __restrict__ Obuf) {
  __shared__ __attribute__((aligned(16))) bf16 Ks[2][64 * 128];
  __shared__ __attribute__((aligned(16))) bf16 Vs[2][128 * 64];
  const int t = threadIdx.x, w = t >> 6, l = t & 63;
  const int lo = l & 15, hi = l >> 4;
  const int bh = blockIdx.x;  // b*16+h
  const int qt = blockIdx.y;  // 128-row q tile
  const int li = blockIdx.z;
  const int b = bh >> 4, h = bh & 15;
  const float C2 = 0.08838834764831845f * 1.44269504f;
  const float M2 = 64.0f * C2;
  const bf16 one_ = (bf16)1.0f;
  const bf16x8 ones8 = {one_, one_, one_, one_, one_, one_, one_, one_};

  bf16x8 qf[2][4];
#pragma unroll
  for (int qs = 0; qs < 2; ++qs) {
    const bf16* qptr =
        Q + ((size_t)bh * 1024 + qt * 128 + w * 32 + qs * 16 + lo) * 128;
#pragma unroll
    for (int db = 0; db < 4; ++db)
      qf[qs][db] = *(const bf16x8*)(qptr + db * 32 + hi * 8);
  }

  int krow[4], kcl[4], vrow[4], vcl[4];
#pragma unroll
  for (int p = 0; p < 4; ++p) {
    int id = p * 256 + t;
    krow[p] = id >> 4;
    kcl[p] = (id & 15) ^ (krow[p] & 7);
    vrow[p] = id >> 3;
    vcl[p] = (id & 7) ^ (vrow[p] & 7);
  }

  const bf16* Kl = Kb + ((size_t)li * 32 + bh) * (size_t)131072;
  const bf16* Vl = Vt + ((size_t)li * 32 + bh) * (size_t)131072;

  f32x4 dacc[2];  // denominator accumulators (per q-subtile)
  f32x4 oacc[2][8];
#pragma unroll
  for (int qs = 0; qs < 2; ++qs) {
#pragma unroll
    for (int q = 0; q < 4; ++q) dacc[qs][q] = 0.f;
#pragma unroll
    for (int dc = 0; dc < 8; ++dc)
#pragma unroll
      for (int q = 0; q < 4; ++q) oacc[qs][dc][q] = 0.f;
  }

  auto stage = [&](int bi, int kt2) {
    const bf16* Ksrc = Kl + (size_t)kt2 * 8192;
#pragma unroll
    for (int p = 0; p < 4; ++p)
      gload_lds16(Ksrc + (size_t)krow[p] * 128 + kcl[p] * 8,
                  &Ks[bi][(p * 256 + w * 64) * 8]);
#pragma unroll
    for (int p = 0; p < 4; ++p)
      gload_lds16(Vl + (size_t)vrow[p] * 1024 + kt2 * 64 + vcl[p] * 8,
                  &Vs[bi][(p * 256 + w * 64) * 8]);
  };

  // fixed-max softmax + P-pack (no denominator work here anymore)
  auto softmax_step = [&](f32x4 (&sa)[4], bf16x8 (&pf2)[2]) {
    bf16x4v pk[4];
#pragma unroll
    for (int kc = 0; kc < 4; ++kc) {
#pragma unroll
      for (int i = 0; i < 4; ++i) {
        float pf_ = __builtin_amdgcn_exp2f(fmaf(sa[kc][i], C2, -M2));
        pk[kc][i] = (bf16)pf_;
      }
    }
    pf2[0] = __builtin_shufflevector(pk[0], pk[1], 0, 1, 2, 3, 4, 5, 6, 7);
    pf2[1] = __builtin_shufflevector(pk[2], pk[3], 0, 1, 2, 3, 4, 5, 6, 7);
  };

  stage(0, 0);
  int cur = 0;
  for (int kt = 0; kt < 16; ++kt) {
    if (kt < 15) {
      stage(cur ^ 1, kt + 1);
      asm volatile("s_waitcnt vmcnt(8)" ::: "memory");
    } else {
      asm volatile("s_waitcnt vmcnt(0)" ::: "memory");
    }
    __builtin_amdgcn_s_barrier();
    __builtin_amdgcn_sched_barrier(0);

    f32x4 sa[2][4];
#pragma unroll
    for (int qs = 0; qs < 2; ++qs)
#pragma unroll
      for (int kc = 0; kc < 4; ++kc)
#pragma unroll
        for (int q = 0; q < 4; ++q) sa[qs][kc][q] = 0.f;
    __builtin_amdgcn_s_setprio(1);
#pragma unroll
    for (int kc = 0; kc < 4; ++kc) {
      int row = kc * 16 + lo;
#pragma unroll
      for (int db = 0; db < 4; ++db) {
        int ch = (db * 4 + hi) ^ (row & 7);
        bf16x8 kf = *(const bf16x8*)&Ks[cur][row * 128 + ch * 8];
        sa[0][kc] = mfma16(kf, qf[0][db], sa[0][kc]);
        sa[1][kc] = mfma16(kf, qf[1][db], sa[1][kc]);
      }
    }
    __builtin_amdgcn_s_setprio(0);

    bf16x8 pfr[2][2];
    softmax_step(sa[0], pfr[0]);
    softmax_step(sa[1], pfr[1]);

    __builtin_amdgcn_s_setprio(1);
#pragma unroll
    for (int kvc = 0; kvc < 2; ++kvc) {
      // denominator: C[q][*] += sum_k P[q][k] (ones B-fragment)
      dacc[0] = mfma16(pfr[0][kvc], ones8, dacc[0]);
      dacc[1] = mfma16(pfr[1][kvc], ones8, dacc[1]);
#pragma unroll
      for (int dc = 0; dc < 8; ++dc) {
        int rowv = dc * 16 + lo;
        int ch = (kvc * 4 + hi) ^ (rowv & 7);
        bf16x8 vf = *(const bf16x8*)&Vs[cur][rowv * 64 + ch * 8];
        oacc[0][dc] = mfma16(pfr[0][kvc], vf, oacc[0][dc]);
        oacc[1][dc] = mfma16(pfr[1][kvc], vf, oacc[1][dc]);
      }
    }
    __builtin_amdgcn_s_setprio(0);
    __builtin_amdgcn_s_barrier();
    cur ^= 1;
  }

  float wl = lw[b * 4 + li];
#pragma unroll
  for (int qs = 0; qs < 2; ++qs) {
    float inv[4];
#pragma unroll
    for (int i = 0; i < 4; ++i) inv[i] = wl / dacc[qs][i];
#pragma unroll
    for (int dc = 0; dc < 8; ++dc) {
      int col = h * 128 + dc * 16 + lo;
#pragma unroll
      for (int i = 0; i < 4; ++i) {
        int srow = qt * 128 + w * 32 + qs * 16 + hi * 4 + i;
        Obuf[((size_t)(li * 2 + b) * 1024 + srow) * 2048 + col] =
            (bf16)(oacc[qs][dc][i] * inv[i]);
      }
    }
  }
}

// ---------------- layer combine: comb = sum_l Obuf[l] ----------------
__global__ __launch_bounds__(256) void comb_kernel(const bf16* __restrict__ Obuf,
                                                   bf16* __restrict__ comb) {
  size_t i = ((size_t)blockIdx.x * 256 + threadIdx.x) * 8;
  bf16x8 a0 = *(const bf16x8*)(Obuf + i);
  bf16x8 a1 = *(const bf16x8*)(Obuf + 4194304 + i);
  bf16x8 a2 = *(const bf16x8*)(Obuf + 8388608 + i);
  bf16x8 a3 = *(const bf16x8*)(Obuf + 12582912 + i);
  bf16x8 o;
#pragma unroll
  for (int j = 0; j < 8; ++j)
    o[j] = (bf16)((float)a0[j] + (float)a1[j] + (float)a2[j] + (float)a3[j]);
  *(bf16x8*)(comb + i) = o;
}

// ---------------------------------------------------------------------------
extern "C" void kernel_launch(void* const* d_in, const int* in_sizes, int n_in,
                              void* d_out, int out_size, void* d_ws, size_t ws_size,
                              hipStream_t stream) {
  (void)in_sizes; (void)n_in; (void)out_size; (void)ws_size;
  const float* hs = (const float*)d_in[0];     // [2,1024,2048]
  const float* prev = (const float*)d_in[1];   // [4,2,1024,2048]
  const float* Wq = (const float*)d_in[2];
  const float* bq = (const float*)d_in[3];
  const float* Wk = (const float*)d_in[4];
  const float* bk = (const float*)d_in[5];
  const float* Wv = (const float*)d_in[6];
  const float* bv = (const float*)d_in[7];
  const float* Wo = (const float*)d_in[8];
  const float* bo = (const float*)d_in[9];
  const float* Wg = (const float*)d_in[10];
  float* out = (float*)d_out;

  char* ws = (char*)d_ws;
  bf16* hs_bf = (bf16*)(ws + 0);                  //  8MB ; later comb
  bf16* prev_bf = (bf16*)(ws + 8388608);          // 32MB ; later Obuf
  bf16* WqT = (bf16*)(ws + 41943040);             //  8MB
  bf16* WkT = (bf16*)(ws + 50331648);             //  8MB
  bf16* WvT = (bf16*)(ws + 58720256);             //  8MB
  bf16* Qbf = (bf16*)(ws + 67108864);             //  8MB (rope'd head-major Q, direct from GEMM)
  bf16* WoT = (bf16*)(ws + 75497472);             //  8MB
  bf16* Kbf = (bf16*)(ws + 83886080);             // 32MB final rope'd K (from gemm_kv)
  bf16* Vt = (bf16*)(ws + 117440512);             // 32MB (V^T, sigma-permuted)
  float* cosT = (float*)(ws + 150994944);         // 256KB
  float* sinT = (float*)(ws + 151257088);         // 256KB
  float* part = (float*)(ws + 151519232);         // 128KB
  float* meanb = (float*)(ws + 151650304);        //  16KB
  float* lwbuf = (float*)(ws + 151666688);        //  256B
  bf16* Obuf = prev_bf;          // prev_bf dead after gemm_kv
  bf16* comb = (bf16*)(ws + 0);  // hs_bf dead after Q-GEMM

  // 1) dtype conversions
  cvt_kernel<<<4096, 256, 0, stream>>>(hs, hs_bf, 2048 * 2048 / 4);
  cvt_kernel<<<16384, 256, 0, stream>>>(prev, prev_bf, 8192 * 2048 / 4);

  // 2) weight transposes (one launch, z-indexed)
  twt4_kernel<<<dim3(32, 32, 4), 256, 0, stream>>>(Wq, Wk, Wv, Wo, WqT, WkT,
                                                   WvT, WoT);

  // 3) RoPE tables + gate
  rope_table_kernel<<<1024, 64, 0, stream>>>(cosT, sinT);
  mean_part_kernel<<<dim3(16, 8), 256, 0, stream>>>(hs, part);
  mean_fin_kernel<<<16, 256, 0, stream>>>(part, meanb);
  gate_kernel<<<1, 256, 0, stream>>>(meanb, Wg, lwbuf);

  // 4) projections: Q (rope fused) via 128^2; K+V fused 8-phase (rope'd K)
  gemm_kernel<4><<<dim3(16, 16), 256, 0, stream>>>(hs_bf, WqT, bq, Qbf, 2048,
                                                   2048, 2048, cosT, sinT);
  gemm_kv_kernel<<<512, 512, 0, stream>>>(prev_bf, WkT, WvT, bk, bv, cosT, sinT,
                                          Kbf, Vt);

  // 5) attention: 128 q-rows per block, dbuf K/V (R10 structure)
  attn_kernel<<<dim3(32, 8, 4), 256, 0, stream>>>(Qbf, Kbf, Vt, lwbuf, Obuf);

  // 6) combine layers
  comb_kernel<<<2048, 256, 0, stream>>>(Obuf, comb);

  // 7) output projection -> fp32 d_out
  gemm_kernel<1><<<dim3(16, 16), 256, 0, stream>>>(comb, WoT, bo, out, 2048,
                                                   2048, 2048, nullptr, nullptr);
}